// Round 1
// baseline (1501.005 us; speedup 1.0000x reference)
//
#include <hip/hip_runtime.h>
#include <stdint.h>
#include <stddef.h>

#define S_LEN 2048
#define BATCH 2
#define NHEADS 32
#define NKV 8
#define HD 128
#define HIDDEN 4096
#define T_TOK (BATCH * S_LEN)

typedef unsigned short u16;
typedef __attribute__((ext_vector_type(4))) float f32x4;
typedef __attribute__((ext_vector_type(8))) short s16x8;
typedef __attribute__((ext_vector_type(4))) unsigned short u16x4;

__device__ __forceinline__ u16 f2bf(float f) {
  unsigned int u = __builtin_bit_cast(unsigned int, f);
  unsigned int r = (u + 0x7FFFu + ((u >> 16) & 1u)) >> 16;
  return (u16)r;
}
__device__ __forceinline__ float bf2f(u16 h) {
  return __builtin_bit_cast(float, ((unsigned int)h) << 16);
}

// global -> LDS direct copy, 16B per lane. LDS dest must be wave-uniform base;
// HW writes base + lane*16 (guide §5).
__device__ __forceinline__ void gload16(const void* g, void* l) {
  __builtin_amdgcn_global_load_lds((__attribute__((address_space(1))) void*)g,
                                   (__attribute__((address_space(3))) void*)l,
                                   16, 0, 0);
}

// ---------------- convert f32 -> bf16 (8 elems / thread) ----------------
__global__ __launch_bounds__(256) void k_convert(const float* __restrict__ in,
                                                 u16* __restrict__ out, int n8) {
  int i = blockIdx.x * 256 + threadIdx.x;
  if (i >= n8) return;
  float4 a = ((const float4*)in)[i * 2];
  float4 b = ((const float4*)in)[i * 2 + 1];
  u16x4 lo = {f2bf(a.x), f2bf(a.y), f2bf(a.z), f2bf(a.w)};
  u16x4 hi = {f2bf(b.x), f2bf(b.y), f2bf(b.z), f2bf(b.w)};
  ((u16x4*)out)[i * 2] = lo;
  ((u16x4*)out)[i * 2 + 1] = hi;
}

// ------------- transpose-convert W [K][N] f32 -> Wt [N][K] bf16 ----------
__global__ __launch_bounds__(256) void k_transpose_w(const float* __restrict__ W,
                                                     u16* __restrict__ Wt, int K,
                                                     int N, int outRowOff,
                                                     int outStride) {
  __shared__ float tl[32][33];
  int k0 = blockIdx.x * 32, n0 = blockIdx.y * 32;
  int t = threadIdx.x;
  int r = t >> 3, c4 = (t & 7) * 4;
  float4 v = *(const float4*)&W[(size_t)(k0 + r) * N + n0 + c4];
  tl[r][c4] = v.x; tl[r][c4 + 1] = v.y; tl[r][c4 + 2] = v.z; tl[r][c4 + 3] = v.w;
  __syncthreads();
  u16x4 o = {f2bf(tl[c4][r]), f2bf(tl[c4 + 1][r]), f2bf(tl[c4 + 2][r]),
             f2bf(tl[c4 + 3][r])};
  *(u16x4*)&Wt[(size_t)(outRowOff + n0 + r) * outStride + k0 + c4] = o;
}

// ---------------- RoPE cos/sin table: tab[s][0:64]=cos, [64:128]=sin -----
__global__ __launch_bounds__(256) void k_rope_tab(const int* __restrict__ pos,
                                                  float* __restrict__ tab) {
  int i = blockIdx.x * 256 + threadIdx.x;  // S*64
  int s = i >> 6, l = i & 63;
  float p = (float)pos[s];
  // inv_freq = 10000^(-2l/128) = exp(-l * ln(10000)/64)
  float ang = p * expf(-(float)l * 0.14391156516342163f);
  tab[s * 128 + l] = cosf(ang);
  tab[s * 128 + 64 + l] = sinf(ang);
}

// ------- m97-style GEMM: C[M][N] = A[M][K] * Bt[N][K]^T  (bf16 in) -------
template <typename OutT>
__global__ __launch_bounds__(256) void k_gemm_bt(const u16* __restrict__ A,
                                                 const u16* __restrict__ Bt,
                                                 OutT* __restrict__ C, int M,
                                                 int N, int K) {
  __shared__ u16 As[128 * 32];
  __shared__ u16 Bs[128 * 32];
  int nbn = N >> 7;
  int bm = blockIdx.x / nbn, bn = blockIdx.x % nbn;
  int tid = threadIdx.x, wave = tid >> 6, lane = tid & 63;
  int g = lane >> 4, c = lane & 15;
  int wr = wave >> 1, wc = wave & 1;
  f32x4 acc[4][4];
#pragma unroll
  for (int m = 0; m < 4; m++)
#pragma unroll
    for (int n = 0; n < 4; n++) acc[m][n] = (f32x4){0.f, 0.f, 0.f, 0.f};

  int srow = wave * 32 + (lane >> 2);  // staging row (issue 0); issue 1 = +16
  int scol = (lane & 3) * 8;
  const u16* Ap = A + (size_t)(bm * 128 + srow) * K + scol;
  const u16* Bp = Bt + (size_t)(bn * 128 + srow) * K + scol;

  for (int kt = 0; kt < K; kt += 32) {
    __syncthreads();
    gload16(Ap + kt, &As[wave * 1024]);
    gload16(Ap + kt + (size_t)16 * K, &As[wave * 1024 + 512]);
    gload16(Bp + kt, &Bs[wave * 1024]);
    gload16(Bp + kt + (size_t)16 * K, &Bs[wave * 1024 + 512]);
    __syncthreads();
    s16x8 af[4], bfr[4];
#pragma unroll
    for (int m = 0; m < 4; m++)
      af[m] = *(const s16x8*)&As[(wr * 64 + m * 16 + c) * 32 + g * 8];
#pragma unroll
    for (int n = 0; n < 4; n++)
      bfr[n] = *(const s16x8*)&Bs[(wc * 64 + n * 16 + c) * 32 + g * 8];
#pragma unroll
    for (int m = 0; m < 4; m++)
#pragma unroll
      for (int n = 0; n < 4; n++)
        acc[m][n] =
            __builtin_amdgcn_mfma_f32_16x16x32_bf16(af[m], bfr[n], acc[m][n], 0, 0, 0);
  }
#pragma unroll
  for (int m = 0; m < 4; m++)
#pragma unroll
    for (int n = 0; n < 4; n++) {
      size_t row = (size_t)bm * 128 + wr * 64 + m * 16 + g * 4;
      size_t col = (size_t)bn * 128 + wc * 64 + n * 16 + c;
#pragma unroll
      for (int r = 0; r < 4; r++) {
        float v = acc[m][n][r];
        if constexpr (sizeof(OutT) == 2)
          C[(row + r) * N + col] = (OutT)f2bf(v);
        else
          C[(row + r) * N + col] = (OutT)v;
      }
    }
}

// ------------- fused per-head RMSNorm + RoPE (in-place, bf16) ------------
__global__ __launch_bounds__(256) void k_rmsrope(u16* __restrict__ QK,
                                                 const float* __restrict__ w,
                                                 const float* __restrict__ tab,
                                                 int H, int rowStride) {
  int row = blockIdx.x * 4 + (threadIdx.x >> 6);
  int lane = threadIdx.x & 63;
  int t = row / H, h = row - t * H;
  int s = t & (S_LEN - 1);
  u16* p = QK + (size_t)t * rowStride + h * HD;
  float x1 = bf2f(p[lane]), x2 = bf2f(p[lane + 64]);
  float ss = x1 * x1 + x2 * x2;
#pragma unroll
  for (int o = 32; o >= 1; o >>= 1) ss += __shfl_xor(ss, o);
  float inv = rsqrtf(ss * (1.0f / 128.0f) + 1e-6f);
  float y1 = x1 * inv * w[lane], y2 = x2 * inv * w[lane + 64];
  float cs = tab[s * 128 + lane], sn = tab[s * 128 + 64 + lane];
  p[lane] = f2bf(y1 * cs - y2 * sn);
  p[lane + 64] = f2bf(y2 * cs + y1 * sn);
}

// --------- transpose V: KV[t][1024 + kh*128 + d] -> Vt[bkh*128+d][s] -----
__global__ __launch_bounds__(256) void k_transpose_v(const u16* __restrict__ KV,
                                                     u16* __restrict__ Vt) {
  __shared__ u16 tl[32][40];
  int bkh = blockIdx.x;
  int s0 = blockIdx.y * 32, d0 = blockIdx.z * 32;
  int b = bkh >> 3, kh = bkh & 7;
  int t = threadIdx.x, r = t >> 3, c4 = (t & 7) * 4;
  const u16* src =
      KV + (size_t)(b * S_LEN + s0 + r) * 2048 + 1024 + kh * HD + d0 + c4;
  u16x4 v = *(const u16x4*)src;
  tl[r][c4] = v[0]; tl[r][c4 + 1] = v[1]; tl[r][c4 + 2] = v[2]; tl[r][c4 + 3] = v[3];
  __syncthreads();
  u16x4 o = {tl[c4][r], tl[c4 + 1][r], tl[c4 + 2][r], tl[c4 + 3][r]};
  *(u16x4*)&Vt[(size_t)(bkh * HD + d0 + r) * S_LEN + s0 + c4] = o;
}

// --------------------------- causal GQA attention ------------------------
// One wave = 16 q rows of one (b,h). Swapped QK^T: S^T = mfma(K, Q):
// per-lane q = lane&15 (=c), k = kb + sub*16 + 4g + r.  PV: O^T = mfma(Vt, P^T).
__global__ __launch_bounds__(256) void k_attn(const u16* __restrict__ Q,
                                              const u16* __restrict__ KV,
                                              const u16* __restrict__ Vt,
                                              u16* __restrict__ Oact) {
  int bid = blockIdx.x;
  int qt = bid & 31;          // S/64
  int bh = bid >> 5;
  int h = bh & 31, b = bh >> 5;
  int kh = h >> 2;
  int wave = threadIdx.x >> 6, lane = threadIdx.x & 63;
  int g = lane >> 4, c = lane & 15;
  int q0 = qt * 64 + wave * 16;
  const float scale = 0.08838834764831845f;

  s16x8 qf[4];
  const u16* Qb = Q + (size_t)(b * S_LEN + q0 + c) * 4096 + h * HD + g * 8;
#pragma unroll
  for (int st = 0; st < 4; st++) qf[st] = *(const s16x8*)(Qb + st * 32);

  f32x4 o[8];
#pragma unroll
  for (int dt = 0; dt < 8; dt++) o[dt] = (f32x4){0.f, 0.f, 0.f, 0.f};
  float m = -1e30f, l = 0.f;

  const u16* Kb = KV + (size_t)(b * S_LEN + c) * 2048 + kh * HD + g * 8;
  const u16* Vb = Vt + ((size_t)(b * 8 + kh) * HD + c) * S_LEN + g * 8;

  int nch = (q0 + 47) >> 5;
  for (int ch = 0; ch < nch; ch++) {
    int kb = ch * 32;
    f32x4 s0 = (f32x4){0.f, 0.f, 0.f, 0.f}, s1 = (f32x4){0.f, 0.f, 0.f, 0.f};
    const u16* Kp = Kb + (size_t)kb * 2048;
#pragma unroll
    for (int st = 0; st < 4; st++) {
      s16x8 k0 = *(const s16x8*)(Kp + st * 32);
      s16x8 k1 = *(const s16x8*)(Kp + (size_t)16 * 2048 + st * 32);
      s0 = __builtin_amdgcn_mfma_f32_16x16x32_bf16(k0, qf[st], s0, 0, 0, 0);
      s1 = __builtin_amdgcn_mfma_f32_16x16x32_bf16(k1, qf[st], s1, 0, 0, 0);
    }
    if (kb + 31 > q0) {
#pragma unroll
      for (int r = 0; r < 4; r++) {
        int kk = kb + 4 * g + r;
        s0[r] = (kk <= q0 + c) ? s0[r] * scale : -1e30f;
        s1[r] = (kk + 16 <= q0 + c) ? s1[r] * scale : -1e30f;
      }
    } else {
#pragma unroll
      for (int r = 0; r < 4; r++) { s0[r] *= scale; s1[r] *= scale; }
    }
    float mx = -1e30f;
#pragma unroll
    for (int r = 0; r < 4; r++) mx = fmaxf(mx, fmaxf(s0[r], s1[r]));
    mx = fmaxf(mx, __shfl_xor(mx, 16));
    mx = fmaxf(mx, __shfl_xor(mx, 32));
    float mnew = fmaxf(m, mx);
    float corr = __expf(m - mnew);
    float p0[4], p1[4];
    float rs = 0.f;
#pragma unroll
    for (int r = 0; r < 4; r++) {
      p0[r] = __expf(s0[r] - mnew);
      p1[r] = __expf(s1[r] - mnew);
      rs += p0[r] + p1[r];
    }
    rs += __shfl_xor(rs, 16);
    rs += __shfl_xor(rs, 32);
    l = l * corr + rs;
    m = mnew;
    // repack P^T (C-layout) into 16x16x32 B-fragment: k = 8g+j per lane
    s16x8 pf;
#pragma unroll
    for (int j2 = 0; j2 < 2; j2++) {
      int src = c + 16 * ((2 * g + j2) & 3);
#pragma unroll
      for (int r = 0; r < 4; r++) {
        float v0 = __shfl(p0[r], src);
        float v1 = __shfl(p1[r], src);
        pf[j2 * 4 + r] = (short)f2bf(g < 2 ? v0 : v1);
      }
    }
#pragma unroll
    for (int dt = 0; dt < 8; dt++) {
      o[dt][0] *= corr; o[dt][1] *= corr; o[dt][2] *= corr; o[dt][3] *= corr;
    }
    const u16* Vp = Vb + kb;
#pragma unroll
    for (int dt = 0; dt < 8; dt++) {
      s16x8 vf = *(const s16x8*)(Vp + (size_t)dt * 16 * S_LEN);
      o[dt] = __builtin_amdgcn_mfma_f32_16x16x32_bf16(vf, pf, o[dt], 0, 0, 0);
    }
  }
  float linv = 1.0f / l;
  u16* Op = Oact + (size_t)(b * S_LEN + q0 + c) * 4096 + h * HD + 4 * g;
#pragma unroll
  for (int dt = 0; dt < 8; dt++) {
    u16x4 w4 = {f2bf(o[dt][0] * linv), f2bf(o[dt][1] * linv),
                f2bf(o[dt][2] * linv), f2bf(o[dt][3] * linv)};
    *(u16x4*)(Op + dt * 16) = w4;
  }
}

extern "C" void kernel_launch(void* const* d_in, const int* in_sizes, int n_in,
                              void* d_out, int out_size, void* d_ws,
                              size_t ws_size, hipStream_t stream) {
  (void)in_sizes; (void)n_in; (void)out_size; (void)ws_size;
  const float* X = (const float*)d_in[0];
  const int* pos = (const int*)d_in[1];
  const float* Wq = (const float*)d_in[2];
  const float* Wk = (const float*)d_in[3];
  const float* Wv = (const float*)d_in[4];
  const float* Wo = (const float*)d_in[5];
  const float* qw = (const float*)d_in[6];
  const float* kw = (const float*)d_in[7];
  float* out = (float*)d_out;
  char* ws = (char*)d_ws;

  const size_t MB = 1024ull * 1024ull;
  u16* Xb    = (u16*)(ws + 0 * MB);     // [4096][4096] bf16   32 MiB
  u16* WqT   = (u16*)(ws + 32 * MB);    // [4096][4096]        32 MiB
  u16* WkvT  = (u16*)(ws + 64 * MB);    // [2048][4096]        16 MiB
  u16* WoT   = (u16*)(ws + 80 * MB);    // [4096][4096]        32 MiB
  u16* Qb    = (u16*)(ws + 112 * MB);   // [4096][4096]        32 MiB
  u16* KVb   = (u16*)(ws + 144 * MB);   // [4096][2048]        16 MiB
  u16* Vt    = (u16*)(ws + 160 * MB);   // [16*128][2048]       8 MiB
  u16* Oact  = (u16*)(ws + 168 * MB);   // [4096][4096]        32 MiB
  float* tab = (float*)(ws + 200 * MB); // [2048][128]          1 MiB

  // 1) converts / transposes
  k_convert<<<8192, 256, 0, stream>>>(X, Xb, (T_TOK * HIDDEN) / 8);
  k_transpose_w<<<dim3(128, 128), 256, 0, stream>>>(Wq, WqT, 4096, 4096, 0, 4096);
  k_transpose_w<<<dim3(128, 32), 256, 0, stream>>>(Wk, WkvT, 4096, 1024, 0, 4096);
  k_transpose_w<<<dim3(128, 32), 256, 0, stream>>>(Wv, WkvT, 4096, 1024, 1024, 4096);
  k_transpose_w<<<dim3(128, 128), 256, 0, stream>>>(Wo, WoT, 4096, 4096, 0, 4096);
  k_rope_tab<<<512, 256, 0, stream>>>(pos, tab);

  // 2) QKV projections (bf16 out)
  k_gemm_bt<u16><<<32 * 32, 256, 0, stream>>>(Xb, WqT, Qb, 4096, 4096, 4096);
  k_gemm_bt<u16><<<32 * 16, 256, 0, stream>>>(Xb, WkvT, KVb, 4096, 2048, 4096);

  // 3) RMSNorm + RoPE (in place)
  k_rmsrope<<<(T_TOK * NHEADS) / 4, 256, 0, stream>>>(Qb, qw, tab, NHEADS, 4096);
  k_rmsrope<<<(T_TOK * NKV) / 4, 256, 0, stream>>>(KVb, kw, tab, NKV, 2048);

  // 4) V transpose for PV operand
  k_transpose_v<<<dim3(16, 64, 4), 256, 0, stream>>>(KVb, Vt);

  // 5) causal GQA attention
  k_attn<<<BATCH * NHEADS * (S_LEN / 64), 256, 0, stream>>>(Qb, KVb, Vt, Oact);

  // 6) output projection (f32 out)
  k_gemm_bt<float><<<32 * 32, 256, 0, stream>>>(Oact, WoT, out, 4096, 4096, 4096);
}

// Round 2
// 935.957 us; speedup vs baseline: 1.6037x; 1.6037x over previous
//
#include <hip/hip_runtime.h>
#include <stdint.h>
#include <stddef.h>

#define S_LEN 2048
#define BATCH 2
#define NHEADS 32
#define NKV 8
#define HD 128
#define HIDDEN 4096
#define T_TOK (BATCH * S_LEN)

typedef unsigned short u16;
typedef __attribute__((ext_vector_type(4))) float f32x4;
typedef __attribute__((ext_vector_type(8))) short s16x8;
typedef __attribute__((ext_vector_type(4))) unsigned short u16x4;

__device__ __forceinline__ u16 f2bf(float f) {
  unsigned int u = __builtin_bit_cast(unsigned int, f);
  unsigned int r = (u + 0x7FFFu + ((u >> 16) & 1u)) >> 16;
  return (u16)r;
}
__device__ __forceinline__ float bf2f(u16 h) {
  return __builtin_bit_cast(float, ((unsigned int)h) << 16);
}

// global -> LDS direct copy, 16B per lane. LDS dest is wave-uniform base;
// HW writes base + lane*16. Global source IS per-lane (pre-swizzle there).
__device__ __forceinline__ void gload16(const void* g, void* l) {
  __builtin_amdgcn_global_load_lds((__attribute__((address_space(1))) void*)g,
                                   (__attribute__((address_space(3))) void*)l,
                                   16, 0, 0);
}

// ---------------- convert f32 -> bf16 (8 elems / thread) ----------------
__global__ __launch_bounds__(256) void k_convert(const float* __restrict__ in,
                                                 u16* __restrict__ out, int n8) {
  int i = blockIdx.x * 256 + threadIdx.x;
  if (i >= n8) return;
  float4 a = ((const float4*)in)[i * 2];
  float4 b = ((const float4*)in)[i * 2 + 1];
  u16x4 lo = {f2bf(a.x), f2bf(a.y), f2bf(a.z), f2bf(a.w)};
  u16x4 hi = {f2bf(b.x), f2bf(b.y), f2bf(b.z), f2bf(b.w)};
  ((u16x4*)out)[i * 2] = lo;
  ((u16x4*)out)[i * 2 + 1] = hi;
}

// ------------- transpose-convert W [K][N] f32 -> Wt [N][K] bf16 ----------
__global__ __launch_bounds__(256) void k_transpose_w(const float* __restrict__ W,
                                                     u16* __restrict__ Wt, int K,
                                                     int N, int outRowOff,
                                                     int outStride) {
  __shared__ float tl[32][33];
  int k0 = blockIdx.x * 32, n0 = blockIdx.y * 32;
  int t = threadIdx.x;
  int r = t >> 3, c4 = (t & 7) * 4;
  float4 v = *(const float4*)&W[(size_t)(k0 + r) * N + n0 + c4];
  tl[r][c4] = v.x; tl[r][c4 + 1] = v.y; tl[r][c4 + 2] = v.z; tl[r][c4 + 3] = v.w;
  __syncthreads();
  u16x4 o = {f2bf(tl[c4][r]), f2bf(tl[c4 + 1][r]), f2bf(tl[c4 + 2][r]),
             f2bf(tl[c4 + 3][r])};
  *(u16x4*)&Wt[(size_t)(outRowOff + n0 + r) * outStride + k0 + c4] = o;
}

// ---------------- RoPE cos/sin table: tab[s][0:64]=cos, [64:128]=sin -----
__global__ __launch_bounds__(256) void k_rope_tab(const int* __restrict__ pos,
                                                  float* __restrict__ tab) {
  int i = blockIdx.x * 256 + threadIdx.x;  // S*64
  int s = i >> 6, l = i & 63;
  float p = (float)pos[s];
  float ang = p * expf(-(float)l * 0.14391156516342163f);
  tab[s * 128 + l] = cosf(ang);
  tab[s * 128 + 64 + l] = sinf(ang);
}

// ------- m97-style GEMM: C[M][N] = A[M][K] * Bt[N][K]^T  (bf16 in) -------
template <typename OutT>
__global__ __launch_bounds__(256) void k_gemm_bt(const u16* __restrict__ A,
                                                 const u16* __restrict__ Bt,
                                                 OutT* __restrict__ C, int M,
                                                 int N, int K) {
  __shared__ u16 As[128 * 32];
  __shared__ u16 Bs[128 * 32];
  int nbn = N >> 7;
  int bm = blockIdx.x / nbn, bn = blockIdx.x % nbn;
  int tid = threadIdx.x, wave = tid >> 6, lane = tid & 63;
  int g = lane >> 4, c = lane & 15;
  int wr = wave >> 1, wc = wave & 1;
  f32x4 acc[4][4];
#pragma unroll
  for (int m = 0; m < 4; m++)
#pragma unroll
    for (int n = 0; n < 4; n++) acc[m][n] = (f32x4){0.f, 0.f, 0.f, 0.f};

  int srow = wave * 32 + (lane >> 2);
  int scol = (lane & 3) * 8;
  const u16* Ap = A + (size_t)(bm * 128 + srow) * K + scol;
  const u16* Bp = Bt + (size_t)(bn * 128 + srow) * K + scol;

  for (int kt = 0; kt < K; kt += 32) {
    __syncthreads();
    gload16(Ap + kt, &As[wave * 1024]);
    gload16(Ap + kt + (size_t)16 * K, &As[wave * 1024 + 512]);
    gload16(Bp + kt, &Bs[wave * 1024]);
    gload16(Bp + kt + (size_t)16 * K, &Bs[wave * 1024 + 512]);
    __syncthreads();
    s16x8 af[4], bfr[4];
#pragma unroll
    for (int m = 0; m < 4; m++)
      af[m] = *(const s16x8*)&As[(wr * 64 + m * 16 + c) * 32 + g * 8];
#pragma unroll
    for (int n = 0; n < 4; n++)
      bfr[n] = *(const s16x8*)&Bs[(wc * 64 + n * 16 + c) * 32 + g * 8];
#pragma unroll
    for (int m = 0; m < 4; m++)
#pragma unroll
      for (int n = 0; n < 4; n++)
        acc[m][n] =
            __builtin_amdgcn_mfma_f32_16x16x32_bf16(af[m], bfr[n], acc[m][n], 0, 0, 0);
  }
#pragma unroll
  for (int m = 0; m < 4; m++)
#pragma unroll
    for (int n = 0; n < 4; n++) {
      size_t row = (size_t)bm * 128 + wr * 64 + m * 16 + g * 4;
      size_t col = (size_t)bn * 128 + wc * 64 + n * 16 + c;
#pragma unroll
      for (int r = 0; r < 4; r++) {
        float v = acc[m][n][r];
        if constexpr (sizeof(OutT) == 2)
          C[(row + r) * N + col] = (OutT)f2bf(v);
        else
          C[(row + r) * N + col] = (OutT)v;
      }
    }
}

// ------------- fused per-head RMSNorm + RoPE (in-place, bf16) ------------
__global__ __launch_bounds__(256) void k_rmsrope(u16* __restrict__ QK,
                                                 const float* __restrict__ w,
                                                 const float* __restrict__ tab,
                                                 int H, int rowStride) {
  int row = blockIdx.x * 4 + (threadIdx.x >> 6);
  int lane = threadIdx.x & 63;
  int t = row / H, h = row - t * H;
  int s = t & (S_LEN - 1);
  u16* p = QK + (size_t)t * rowStride + h * HD;
  float x1 = bf2f(p[lane]), x2 = bf2f(p[lane + 64]);
  float ss = x1 * x1 + x2 * x2;
#pragma unroll
  for (int o = 32; o >= 1; o >>= 1) ss += __shfl_xor(ss, o);
  float inv = rsqrtf(ss * (1.0f / 128.0f) + 1e-6f);
  float y1 = x1 * inv * w[lane], y2 = x2 * inv * w[lane + 64];
  float cs = tab[s * 128 + lane], sn = tab[s * 128 + 64 + lane];
  p[lane] = f2bf(y1 * cs - y2 * sn);
  p[lane + 64] = f2bf(y2 * cs + y1 * sn);
}

// --------- transpose V: KV[t][1024 + kh*128 + d] -> Vt[bkh*128+d][s] -----
__global__ __launch_bounds__(256) void k_transpose_v(const u16* __restrict__ KV,
                                                     u16* __restrict__ Vt) {
  __shared__ u16 tl[32][40];
  int bkh = blockIdx.x;
  int s0 = blockIdx.y * 32, d0 = blockIdx.z * 32;
  int b = bkh >> 3, kh = bkh & 7;
  int t = threadIdx.x, r = t >> 3, c4 = (t & 7) * 4;
  const u16* src =
      KV + (size_t)(b * S_LEN + s0 + r) * 2048 + 1024 + kh * HD + d0 + c4;
  u16x4 v = *(const u16x4*)src;
  tl[r][c4] = v[0]; tl[r][c4 + 1] = v[1]; tl[r][c4 + 2] = v[2]; tl[r][c4 + 3] = v[3];
  __syncthreads();
  u16x4 o = {tl[c4][r], tl[c4 + 1][r], tl[c4 + 2][r], tl[c4 + 3][r]};
  *(u16x4*)&Vt[(size_t)(bkh * HD + d0 + r) * S_LEN + s0 + c4] = o;
}

// --------------------------- causal GQA attention ------------------------
// Block = 4 waves = one (b,h), 64 q rows. Wave w owns 16 q rows.
// Per 64-key chunk: stage K[64][128] and Vt[128][64] into LDS
// (global_load_lds, pre-swizzled source; reads XOR-swizzled byte^=(row&7)<<4).
// Swapped QK^T: S^T = mfma(K,Q), per-lane q = lane&15. PV: O^T = mfma(V^T,P^T).
__global__ __launch_bounds__(256) void k_attn(const u16* __restrict__ Q,
                                              const u16* __restrict__ KV,
                                              const u16* __restrict__ Vt,
                                              u16* __restrict__ Oact) {
  __shared__ u16 Ks[64 * 128];   // [64 keys][128 d], 256 B rows, swizzled
  __shared__ u16 Vs[128 * 64];   // [128 d][64 keys], 128 B rows, swizzled
  int bid = blockIdx.x;
  int qt = bid & 31;  // S/64
  int bh = bid >> 5;
  int h = bh & 31, b = bh >> 5;
  int kh = h >> 2;
  int w = threadIdx.x >> 6, lane = threadIdx.x & 63;
  int g = lane >> 4, c = lane & 15;
  int q0 = qt * 64 + w * 16;
  const float scale = 0.08838834764831845f;

  // Q fragment (B-operand), scale folded in
  s16x8 qf[4];
  const u16* Qp = Q + (size_t)(b * S_LEN + q0 + c) * 4096 + h * HD + g * 8;
#pragma unroll
  for (int st = 0; st < 4; st++) {
    s16x8 raw = *(const s16x8*)(Qp + st * 32);
#pragma unroll
    for (int e = 0; e < 8; e++)
      qf[st][e] = (short)f2bf(bf2f((u16)raw[e]) * scale);
  }

  f32x4 o[8];
#pragma unroll
  for (int dt = 0; dt < 8; dt++) o[dt] = (f32x4){0.f, 0.f, 0.f, 0.f};
  float m = -1e30f, l = 0.f;

  const char* Kg = (const char*)(KV + (size_t)b * S_LEN * 2048 + kh * HD);
  const char* Vg = (const char*)(Vt + (size_t)(b * 8 + kh) * HD * S_LEN);
  char* KsB = (char*)Ks;
  char* VsB = (char*)Vs;

  for (int ch = 0; ch <= qt; ch++) {
    int kb = ch * 64;
    __syncthreads();  // previous chunk's LDS reads done
    // stage K tile: 16 x 1KB instrs (4/wave); rows 4 per instr
#pragma unroll
    for (int j = 0; j < 4; j++) {
      int ins = w * 4 + j;
      int row = ins * 4 + (lane >> 4);
      int bc = ((lane & 15) * 16) ^ ((row & 7) << 4);
      gload16(Kg + (size_t)(kb + row) * 4096 + bc, KsB + ins * 1024);
    }
    // stage V tile: rows 8 per instr (128B rows)
#pragma unroll
    for (int j = 0; j < 4; j++) {
      int ins = w * 4 + j;
      int row = ins * 8 + (lane >> 3);
      int bc = ((lane & 7) * 16) ^ ((row & 7) << 4);
      gload16(Vg + (size_t)row * 4096 + kb * 2 + bc, VsB + ins * 1024);
    }
    __syncthreads();  // vmcnt(0) drained by compiler before barrier

    // QK^T for 4 key-subtiles of 16
    f32x4 s4[4];
#pragma unroll
    for (int sub = 0; sub < 4; sub++) {
      s4[sub] = (f32x4){0.f, 0.f, 0.f, 0.f};
      int row = sub * 16 + c;
      int sw = (row & 7) << 4;
#pragma unroll
      for (int st = 0; st < 4; st++) {
        s16x8 kf = *(const s16x8*)(KsB + row * 256 + ((st * 64 + g * 16) ^ sw));
        s4[sub] = __builtin_amdgcn_mfma_f32_16x16x32_bf16(kf, qf[st], s4[sub], 0, 0, 0);
      }
    }
    if (ch == qt) {  // diagonal chunk: causal mask (scale already in Q)
#pragma unroll
      for (int sub = 0; sub < 4; sub++)
#pragma unroll
        for (int r = 0; r < 4; r++) {
          int kk = kb + sub * 16 + 4 * g + r;
          if (kk > q0 + c) s4[sub][r] = -1e30f;
        }
    }
    // online softmax over row q=c (lanes c, c+16, c+32, c+48)
    float mx = -1e30f;
#pragma unroll
    for (int sub = 0; sub < 4; sub++)
#pragma unroll
      for (int r = 0; r < 4; r++) mx = fmaxf(mx, s4[sub][r]);
    mx = fmaxf(mx, __shfl_xor(mx, 16));
    mx = fmaxf(mx, __shfl_xor(mx, 32));
    float mnew = fmaxf(m, mx);
    float corr = __expf(m - mnew);
    float p[4][4];
    float rs = 0.f;
#pragma unroll
    for (int sub = 0; sub < 4; sub++)
#pragma unroll
      for (int r = 0; r < 4; r++) {
        p[sub][r] = __expf(s4[sub][r] - mnew);
        rs += p[sub][r];
      }
    rs += __shfl_xor(rs, 16);
    rs += __shfl_xor(rs, 32);
    l = l * corr + rs;
    m = mnew;
    // pack P^T into two 16x16x32 B-fragments (k = g*8 + j per lane)
    s16x8 pf[2];
#pragma unroll
    for (int ks = 0; ks < 2; ks++)
#pragma unroll
      for (int j2 = 0; j2 < 2; j2++) {
        int src = c + 16 * ((2 * g + j2) & 3);
#pragma unroll
        for (int r = 0; r < 4; r++) {
          float v0 = __shfl(p[2 * ks][r], src);
          float v1 = __shfl(p[2 * ks + 1][r], src);
          pf[ks][j2 * 4 + r] = (short)f2bf(g < 2 ? v0 : v1);
        }
      }
    // rescale O, then PV
#pragma unroll
    for (int dt = 0; dt < 8; dt++) {
      o[dt][0] *= corr; o[dt][1] *= corr; o[dt][2] *= corr; o[dt][3] *= corr;
    }
#pragma unroll
    for (int dt = 0; dt < 8; dt++) {
      int row = dt * 16 + c;
      int sw = (row & 7) << 4;
#pragma unroll
      for (int ks = 0; ks < 2; ks++) {
        s16x8 vf = *(const s16x8*)(VsB + row * 128 + ((ks * 64 + g * 16) ^ sw));
        o[dt] = __builtin_amdgcn_mfma_f32_16x16x32_bf16(vf, pf[ks], o[dt], 0, 0, 0);
      }
    }
  }
  float linv = 1.0f / l;
  u16* Op = Oact + (size_t)(b * S_LEN + q0 + c) * 4096 + h * HD + 4 * g;
#pragma unroll
  for (int dt = 0; dt < 8; dt++) {
    u16x4 w4 = {f2bf(o[dt][0] * linv), f2bf(o[dt][1] * linv),
                f2bf(o[dt][2] * linv), f2bf(o[dt][3] * linv)};
    *(u16x4*)(Op + dt * 16) = w4;
  }
}

extern "C" void kernel_launch(void* const* d_in, const int* in_sizes, int n_in,
                              void* d_out, int out_size, void* d_ws,
                              size_t ws_size, hipStream_t stream) {
  (void)in_sizes; (void)n_in; (void)out_size; (void)ws_size;
  const float* X = (const float*)d_in[0];
  const int* pos = (const int*)d_in[1];
  const float* Wq = (const float*)d_in[2];
  const float* Wk = (const float*)d_in[3];
  const float* Wv = (const float*)d_in[4];
  const float* Wo = (const float*)d_in[5];
  const float* qw = (const float*)d_in[6];
  const float* kw = (const float*)d_in[7];
  float* out = (float*)d_out;
  char* ws = (char*)d_ws;

  const size_t MB = 1024ull * 1024ull;
  u16* Xb    = (u16*)(ws + 0 * MB);     // [4096][4096] bf16   32 MiB
  u16* WqT   = (u16*)(ws + 32 * MB);    // [4096][4096]        32 MiB
  u16* WkvT  = (u16*)(ws + 64 * MB);    // [2048][4096]        16 MiB
  u16* WoT   = (u16*)(ws + 80 * MB);    // [4096][4096]        32 MiB
  u16* Qb    = (u16*)(ws + 112 * MB);   // [4096][4096]        32 MiB
  u16* KVb   = (u16*)(ws + 144 * MB);   // [4096][2048]        16 MiB
  u16* Vt    = (u16*)(ws + 160 * MB);   // [16*128][2048]       8 MiB
  u16* Oact  = (u16*)(ws + 168 * MB);   // [4096][4096]        32 MiB
  float* tab = (float*)(ws + 200 * MB); // [2048][128]          1 MiB

  // 1) converts / transposes
  k_convert<<<8192, 256, 0, stream>>>(X, Xb, (T_TOK * HIDDEN) / 8);
  k_transpose_w<<<dim3(128, 128), 256, 0, stream>>>(Wq, WqT, 4096, 4096, 0, 4096);
  k_transpose_w<<<dim3(128, 32), 256, 0, stream>>>(Wk, WkvT, 4096, 1024, 0, 4096);
  k_transpose_w<<<dim3(128, 32), 256, 0, stream>>>(Wv, WkvT, 4096, 1024, 1024, 4096);
  k_transpose_w<<<dim3(128, 128), 256, 0, stream>>>(Wo, WoT, 4096, 4096, 0, 4096);
  k_rope_tab<<<512, 256, 0, stream>>>(pos, tab);

  // 2) QKV projections (bf16 out)
  k_gemm_bt<u16><<<32 * 32, 256, 0, stream>>>(Xb, WqT, Qb, 4096, 4096, 4096);
  k_gemm_bt<u16><<<32 * 16, 256, 0, stream>>>(Xb, WkvT, KVb, 4096, 2048, 4096);

  // 3) RMSNorm + RoPE (in place)
  k_rmsrope<<<(T_TOK * NHEADS) / 4, 256, 0, stream>>>(Qb, qw, tab, NHEADS, 4096);
  k_rmsrope<<<(T_TOK * NKV) / 4, 256, 0, stream>>>(KVb, kw, tab, NKV, 2048);

  // 4) V transpose for PV operand
  k_transpose_v<<<dim3(16, 64, 4), 256, 0, stream>>>(KVb, Vt);

  // 5) causal GQA attention (LDS-staged, swizzled)
  k_attn<<<BATCH * NHEADS * (S_LEN / 64), 256, 0, stream>>>(Qb, KVb, Vt, Oact);

  // 6) output projection (f32 out)
  k_gemm_bt<float><<<32 * 32, 256, 0, stream>>>(Oact, WoT, out, 4096, 4096, 4096);
}

// Round 3
// 802.261 us; speedup vs baseline: 1.8710x; 1.1666x over previous
//
#include <hip/hip_runtime.h>
#include <stdint.h>
#include <stddef.h>

#define S_LEN 2048
#define BATCH 2
#define NHEADS 32
#define NKV 8
#define HD 128
#define HIDDEN 4096
#define T_TOK (BATCH * S_LEN)

typedef unsigned short u16;
typedef __attribute__((ext_vector_type(4))) float f32x4;
typedef __attribute__((ext_vector_type(16))) float f32x16;
typedef __attribute__((ext_vector_type(8))) short s16x8;
typedef __attribute__((ext_vector_type(4))) unsigned short u16x4;
typedef __attribute__((ext_vector_type(4))) unsigned int u32x4;

__device__ __forceinline__ u16 f2bf(float f) {
  unsigned int u = __builtin_bit_cast(unsigned int, f);
  unsigned int r = (u + 0x7FFFu + ((u >> 16) & 1u)) >> 16;
  return (u16)r;
}
__device__ __forceinline__ float bf2f(u16 h) {
  return __builtin_bit_cast(float, ((unsigned int)h) << 16);
}

__device__ __forceinline__ void gload16(const void* g, void* l) {
  __builtin_amdgcn_global_load_lds((__attribute__((address_space(1))) void*)g,
                                   (__attribute__((address_space(3))) void*)l,
                                   16, 0, 0);
}

// pack 2 f32 -> u32 of 2 bf16 (lo = a, hi = b)
__device__ __forceinline__ unsigned cvtpk(float a, float b) {
  unsigned r;
  asm("v_cvt_pk_bf16_f32 %0, %1, %2" : "=v"(r) : "v"(a), "v"(b));
  return r;
}
// in: W on all lanes. out: lo = W[lane&31] (half0 bcast), hi = W[32|(lane&31)]
__device__ __forceinline__ void lohi_dup(unsigned W, unsigned& lo, unsigned& hi) {
  unsigned a = W, b = W;
  asm volatile("v_permlane32_swap_b32 %0, %1" : "+v"(a), "+v"(b));
  lo = a; hi = b;
}

// ---------------- convert f32 -> bf16 (8 elems / thread) ----------------
__global__ __launch_bounds__(256) void k_convert(const float* __restrict__ in,
                                                 u16* __restrict__ out, int n8) {
  int i = blockIdx.x * 256 + threadIdx.x;
  if (i >= n8) return;
  float4 a = ((const float4*)in)[i * 2];
  float4 b = ((const float4*)in)[i * 2 + 1];
  u16x4 lo = {f2bf(a.x), f2bf(a.y), f2bf(a.z), f2bf(a.w)};
  u16x4 hi = {f2bf(b.x), f2bf(b.y), f2bf(b.z), f2bf(b.w)};
  ((u16x4*)out)[i * 2] = lo;
  ((u16x4*)out)[i * 2 + 1] = hi;
}

// ------------- transpose-convert W [K][N] f32 -> Wt [N][K] bf16 ----------
__global__ __launch_bounds__(256) void k_transpose_w(const float* __restrict__ W,
                                                     u16* __restrict__ Wt, int K,
                                                     int N, int outRowOff,
                                                     int outStride) {
  __shared__ float tl[32][33];
  int k0 = blockIdx.x * 32, n0 = blockIdx.y * 32;
  int t = threadIdx.x;
  int r = t >> 3, c4 = (t & 7) * 4;
  float4 v = *(const float4*)&W[(size_t)(k0 + r) * N + n0 + c4];
  tl[r][c4] = v.x; tl[r][c4 + 1] = v.y; tl[r][c4 + 2] = v.z; tl[r][c4 + 3] = v.w;
  __syncthreads();
  u16x4 o = {f2bf(tl[c4][r]), f2bf(tl[c4 + 1][r]), f2bf(tl[c4 + 2][r]),
             f2bf(tl[c4 + 3][r])};
  *(u16x4*)&Wt[(size_t)(outRowOff + n0 + r) * outStride + k0 + c4] = o;
}

// ---------------- RoPE cos/sin table: tab[s][0:64]=cos, [64:128]=sin -----
__global__ __launch_bounds__(256) void k_rope_tab(const int* __restrict__ pos,
                                                  float* __restrict__ tab) {
  int i = blockIdx.x * 256 + threadIdx.x;  // S*64
  int s = i >> 6, l = i & 63;
  float p = (float)pos[s];
  float ang = p * expf(-(float)l * 0.14391156516342163f);
  tab[s * 128 + l] = cosf(ang);
  tab[s * 128 + 64 + l] = sinf(ang);
}

// ------- m97-style GEMM: C[M][N] = A[M][K] * Bt[N][K]^T  (bf16 in) -------
template <typename OutT>
__global__ __launch_bounds__(256) void k_gemm_bt(const u16* __restrict__ A,
                                                 const u16* __restrict__ Bt,
                                                 OutT* __restrict__ C, int M,
                                                 int N, int K) {
  __shared__ u16 As[128 * 32];
  __shared__ u16 Bs[128 * 32];
  int nbn = N >> 7;
  int bm = blockIdx.x / nbn, bn = blockIdx.x % nbn;
  int tid = threadIdx.x, wave = tid >> 6, lane = tid & 63;
  int g = lane >> 4, c = lane & 15;
  int wr = wave >> 1, wc = wave & 1;
  f32x4 acc[4][4];
#pragma unroll
  for (int m = 0; m < 4; m++)
#pragma unroll
    for (int n = 0; n < 4; n++) acc[m][n] = (f32x4){0.f, 0.f, 0.f, 0.f};

  int srow = wave * 32 + (lane >> 2);
  int scol = (lane & 3) * 8;
  const u16* Ap = A + (size_t)(bm * 128 + srow) * K + scol;
  const u16* Bp = Bt + (size_t)(bn * 128 + srow) * K + scol;

  for (int kt = 0; kt < K; kt += 32) {
    __syncthreads();
    gload16(Ap + kt, &As[wave * 1024]);
    gload16(Ap + kt + (size_t)16 * K, &As[wave * 1024 + 512]);
    gload16(Bp + kt, &Bs[wave * 1024]);
    gload16(Bp + kt + (size_t)16 * K, &Bs[wave * 1024 + 512]);
    __syncthreads();
    s16x8 af[4], bfr[4];
#pragma unroll
    for (int m = 0; m < 4; m++)
      af[m] = *(const s16x8*)&As[(wr * 64 + m * 16 + c) * 32 + g * 8];
#pragma unroll
    for (int n = 0; n < 4; n++)
      bfr[n] = *(const s16x8*)&Bs[(wc * 64 + n * 16 + c) * 32 + g * 8];
#pragma unroll
    for (int m = 0; m < 4; m++)
#pragma unroll
      for (int n = 0; n < 4; n++)
        acc[m][n] =
            __builtin_amdgcn_mfma_f32_16x16x32_bf16(af[m], bfr[n], acc[m][n], 0, 0, 0);
  }
#pragma unroll
  for (int m = 0; m < 4; m++)
#pragma unroll
    for (int n = 0; n < 4; n++) {
      size_t row = (size_t)bm * 128 + wr * 64 + m * 16 + g * 4;
      size_t col = (size_t)bn * 128 + wc * 64 + n * 16 + c;
#pragma unroll
      for (int r = 0; r < 4; r++) {
        float v = acc[m][n][r];
        if constexpr (sizeof(OutT) == 2)
          C[(row + r) * N + col] = (OutT)f2bf(v);
        else
          C[(row + r) * N + col] = (OutT)v;
      }
    }
}

// ------------- fused per-head RMSNorm + RoPE (in-place, bf16) ------------
__global__ __launch_bounds__(256) void k_rmsrope(u16* __restrict__ QK,
                                                 const float* __restrict__ w,
                                                 const float* __restrict__ tab,
                                                 int H, int rowStride) {
  int row = blockIdx.x * 4 + (threadIdx.x >> 6);
  int lane = threadIdx.x & 63;
  int t = row / H, h = row - t * H;
  int s = t & (S_LEN - 1);
  u16* p = QK + (size_t)t * rowStride + h * HD;
  float x1 = bf2f(p[lane]), x2 = bf2f(p[lane + 64]);
  float ss = x1 * x1 + x2 * x2;
#pragma unroll
  for (int o = 32; o >= 1; o >>= 1) ss += __shfl_xor(ss, o);
  float inv = rsqrtf(ss * (1.0f / 128.0f) + 1e-6f);
  float y1 = x1 * inv * w[lane], y2 = x2 * inv * w[lane + 64];
  float cs = tab[s * 128 + lane], sn = tab[s * 128 + 64 + lane];
  p[lane] = f2bf(y1 * cs - y2 * sn);
  p[lane + 64] = f2bf(y2 * cs + y1 * sn);
}

// --------- transpose V: KV[t][1024 + kh*128 + d] -> Vt[bkh*128+d][s] -----
__global__ __launch_bounds__(256) void k_transpose_v(const u16* __restrict__ KV,
                                                     u16* __restrict__ Vt) {
  __shared__ u16 tl[32][40];
  int bkh = blockIdx.x;
  int s0 = blockIdx.y * 32, d0 = blockIdx.z * 32;
  int b = bkh >> 3, kh = bkh & 7;
  int t = threadIdx.x, r = t >> 3, c4 = (t & 7) * 4;
  const u16* src =
      KV + (size_t)(b * S_LEN + s0 + r) * 2048 + 1024 + kh * HD + d0 + c4;
  u16x4 v = *(const u16x4*)src;
  tl[r][c4] = v[0]; tl[r][c4 + 1] = v[1]; tl[r][c4 + 2] = v[2]; tl[r][c4 + 3] = v[3];
  __syncthreads();
  u16x4 o = {tl[c4][r], tl[c4 + 1][r], tl[c4 + 2][r], tl[c4 + 3][r]};
  *(u16x4*)&Vt[(size_t)(bkh * HD + d0 + r) * S_LEN + s0 + c4] = o;
}

// --------------------------- causal GQA attention ------------------------
// Block = 4 waves, 128 q rows of one (b,h); wave w owns 32 q rows.
// 32x32x16 MFMA, swapped QK^T: S^T = mfma(K,Q) -> per-lane q = lane&31,
// 16 keys per lane per 32-key subtile. Softmax lane-local + 1 xor-32 shfl.
// P repacked to PV B-fragment via cvt_pk_bf16 + permlane32_swap (T12).
// K/V double-buffered in LDS (64 KiB), 1 barrier/chunk (T3-lite).
__global__ __launch_bounds__(256) void k_attn(const u16* __restrict__ Q,
                                              const u16* __restrict__ KV,
                                              const u16* __restrict__ Vt,
                                              u16* __restrict__ Oact) {
  __shared__ u16 Ks[2][64 * 128];   // [64 keys][128 d], 256 B rows, swizzled
  __shared__ u16 Vs[2][128 * 64];   // [128 d][64 keys], 128 B rows, swizzled
  int bid = blockIdx.x;
  int qt = 15 - (bid >> 6);  // longest-first (LPT) over S/128 q-tiles
  int bh = bid & 63;
  int h = bh & 31, b = bh >> 5;
  int kh = h >> 2;
  int w = threadIdx.x >> 6, lane = threadIdx.x & 63;
  int q31 = lane & 31, hh = lane >> 5;
  int qw0 = qt * 128 + w * 32;
  const float scale = 0.08838834764831845f;

  // Q fragments (B operand: q = lane&31, d = dc*16 + hh*8 + e), scale folded
  s16x8 qf[8];
  const u16* Qp = Q + (size_t)(b * S_LEN + qw0 + q31) * 4096 + h * HD + hh * 8;
#pragma unroll
  for (int dc = 0; dc < 8; dc++) {
    s16x8 raw = *(const s16x8*)(Qp + dc * 16);
#pragma unroll
    for (int e = 0; e < 8; e++)
      qf[dc][e] = (short)f2bf(bf2f((u16)raw[e]) * scale);
  }

  f32x16 o[4];
#pragma unroll
  for (int d = 0; d < 4; d++)
#pragma unroll
    for (int r = 0; r < 16; r++) o[d][r] = 0.f;
  float m = -3.0e38f, l = 0.f;

  const char* Kg = (const char*)(KV + (size_t)b * S_LEN * 2048 + kh * HD);
  const char* Vg = (const char*)(Vt + (size_t)(b * 8 + kh) * HD * S_LEN);

  int nch = 2 * qt + 2;

  // prologue: stage chunk 0 into buffer 0
  {
    char* KsB = (char*)Ks[0];
    char* VsB = (char*)Vs[0];
#pragma unroll
    for (int j = 0; j < 4; j++) {
      int ins = w * 4 + j;
      int row = ins * 4 + (lane >> 4);
      int bc = ((lane & 15) * 16) ^ ((row & 7) << 4);
      gload16(Kg + (size_t)row * 4096 + bc, KsB + ins * 1024);
    }
#pragma unroll
    for (int j = 0; j < 4; j++) {
      int ins = w * 4 + j;
      int row = ins * 8 + (lane >> 3);
      int bc = ((lane & 7) * 16) ^ ((row & 7) << 4);
      gload16(Vg + (size_t)row * 4096 + bc, VsB + ins * 1024);
    }
  }

  int cur = 0;
  for (int ch = 0; ch < nch; ch++) {
    int kb = ch * 64;
    __syncthreads();  // drains vmcnt (buf[cur] staged) + prev reads done
    if (ch + 1 < nch) {  // stage next chunk into buf[cur^1], overlapped
      char* KsB = (char*)Ks[cur ^ 1];
      char* VsB = (char*)Vs[cur ^ 1];
      int kb2 = kb + 64;
#pragma unroll
      for (int j = 0; j < 4; j++) {
        int ins = w * 4 + j;
        int row = ins * 4 + (lane >> 4);
        int bc = ((lane & 15) * 16) ^ ((row & 7) << 4);
        gload16(Kg + (size_t)(kb2 + row) * 4096 + bc, KsB + ins * 1024);
      }
#pragma unroll
      for (int j = 0; j < 4; j++) {
        int ins = w * 4 + j;
        int row = ins * 8 + (lane >> 3);
        int bc = ((lane & 7) * 16) ^ ((row & 7) << 4);
        gload16(Vg + (size_t)row * 4096 + (size_t)kb2 * 2 + bc, VsB + ins * 1024);
      }
    }
    if (kb <= qw0 + 31) {  // wave has unmasked work in this chunk
      char* KsB = (char*)Ks[cur];
      char* VsB = (char*)Vs[cur];
      // ---- QK^T: two 32-key subtiles ----
      f32x16 sA, sB;
#pragma unroll
      for (int r = 0; r < 16; r++) { sA[r] = 0.f; sB[r] = 0.f; }
      int sw = (q31 & 7) << 4;
      __builtin_amdgcn_s_setprio(1);
#pragma unroll
      for (int dc = 0; dc < 8; dc++) {
        s16x8 kfA = *(const s16x8*)(KsB + q31 * 256 + ((dc * 32 + hh * 16) ^ sw));
        s16x8 kfB = *(const s16x8*)(KsB + (32 + q31) * 256 + ((dc * 32 + hh * 16) ^ sw));
        sA = __builtin_amdgcn_mfma_f32_32x32x16_bf16(kfA, qf[dc], sA, 0, 0, 0);
        sB = __builtin_amdgcn_mfma_f32_32x32x16_bf16(kfB, qf[dc], sB, 0, 0, 0);
      }
      __builtin_amdgcn_s_setprio(0);
      // ---- causal mask (boundary chunks only) ----
      if (kb + 63 > qw0) {
        int qa = qw0 + q31;
#pragma unroll
        for (int r = 0; r < 16; r++) {
          int krow = (r & 3) + 8 * (r >> 2) + 4 * hh;
          if (kb + krow > qa) sA[r] = -1e30f;
          if (kb + 32 + krow > qa) sB[r] = -1e30f;
        }
      }
      // ---- online softmax (lane-local rows) ----
      float mx = -3.0e38f;
#pragma unroll
      for (int r = 0; r < 16; r++) mx = fmaxf(mx, fmaxf(sA[r], sB[r]));
      mx = fmaxf(mx, __shfl_xor(mx, 32));
      if (!__all(mx - m <= 8.0f)) {  // defer-max (T13)
        float mnew = fmaxf(m, mx);
        float corr = __expf(m - mnew);
        l *= corr;
#pragma unroll
        for (int d = 0; d < 4; d++)
#pragma unroll
          for (int r = 0; r < 16; r++) o[d][r] *= corr;
        m = mnew;
      }
      float rs = 0.f;
#pragma unroll
      for (int r = 0; r < 16; r++) {
        sA[r] = __expf(sA[r] - m); rs += sA[r];
        sB[r] = __expf(sB[r] - m); rs += sB[r];
      }
      rs += __shfl_xor(rs, 32);
      l += rs;
      // ---- repack P -> B-fragments + PV, per 32-key subtile ----
#pragma unroll
      for (int st = 0; st < 2; st++) {
        unsigned Aw[8], Bw[8];
#pragma unroll
        for (int j = 0; j < 8; j++) {
          float p0 = st ? sB[2 * j] : sA[2 * j];
          float p1 = st ? sB[2 * j + 1] : sA[2 * j + 1];
          lohi_dup(cvtpk(p0, p1), Aw[j], Bw[j]);
        }
#pragma unroll
        for (int kc2 = 0; kc2 < 2; kc2++) {
          u32x4 wv;
          wv.x = hh ? Aw[kc2 * 4 + 2] : Aw[kc2 * 4 + 0];
          wv.y = hh ? Aw[kc2 * 4 + 3] : Aw[kc2 * 4 + 1];
          wv.z = hh ? Bw[kc2 * 4 + 2] : Bw[kc2 * 4 + 0];
          wv.w = hh ? Bw[kc2 * 4 + 3] : Bw[kc2 * 4 + 1];
          s16x8 pf = __builtin_bit_cast(s16x8, wv);
          int kc = st * 2 + kc2;
          __builtin_amdgcn_s_setprio(1);
#pragma unroll
          for (int d = 0; d < 4; d++) {
            int row = d * 32 + q31;
            int vsw = (row & 7) << 4;
            s16x8 vf = *(const s16x8*)(VsB + row * 128 + ((kc * 32 + hh * 16) ^ vsw));
            o[d] = __builtin_amdgcn_mfma_f32_32x32x16_bf16(vf, pf, o[d], 0, 0, 0);
          }
          __builtin_amdgcn_s_setprio(0);
        }
      }
    }
    cur ^= 1;
  }
  // ---- epilogue: O^T C-layout -> Oact[token][h*128+d] ----
  float linv = 1.0f / l;
  u16* Op = Oact + (size_t)(b * S_LEN + qw0 + q31) * 4096 + h * HD;
#pragma unroll
  for (int d = 0; d < 4; d++)
#pragma unroll
    for (int g4 = 0; g4 < 4; g4++) {
      int d0 = d * 32 + 8 * g4 + 4 * hh;
      u16x4 w4 = {f2bf(o[d][4 * g4 + 0] * linv), f2bf(o[d][4 * g4 + 1] * linv),
                  f2bf(o[d][4 * g4 + 2] * linv), f2bf(o[d][4 * g4 + 3] * linv)};
      *(u16x4*)(Op + d0) = w4;
    }
}

extern "C" void kernel_launch(void* const* d_in, const int* in_sizes, int n_in,
                              void* d_out, int out_size, void* d_ws,
                              size_t ws_size, hipStream_t stream) {
  (void)in_sizes; (void)n_in; (void)out_size; (void)ws_size;
  const float* X = (const float*)d_in[0];
  const int* pos = (const int*)d_in[1];
  const float* Wq = (const float*)d_in[2];
  const float* Wk = (const float*)d_in[3];
  const float* Wv = (const float*)d_in[4];
  const float* Wo = (const float*)d_in[5];
  const float* qw = (const float*)d_in[6];
  const float* kw = (const float*)d_in[7];
  float* out = (float*)d_out;
  char* ws = (char*)d_ws;

  const size_t MB = 1024ull * 1024ull;
  u16* Xb    = (u16*)(ws + 0 * MB);
  u16* WqT   = (u16*)(ws + 32 * MB);
  u16* WkvT  = (u16*)(ws + 64 * MB);
  u16* WoT   = (u16*)(ws + 80 * MB);
  u16* Qb    = (u16*)(ws + 112 * MB);
  u16* KVb   = (u16*)(ws + 144 * MB);
  u16* Vt    = (u16*)(ws + 160 * MB);
  u16* Oact  = (u16*)(ws + 168 * MB);
  float* tab = (float*)(ws + 200 * MB);

  k_convert<<<8192, 256, 0, stream>>>(X, Xb, (T_TOK * HIDDEN) / 8);
  k_transpose_w<<<dim3(128, 128), 256, 0, stream>>>(Wq, WqT, 4096, 4096, 0, 4096);
  k_transpose_w<<<dim3(128, 32), 256, 0, stream>>>(Wk, WkvT, 4096, 1024, 0, 4096);
  k_transpose_w<<<dim3(128, 32), 256, 0, stream>>>(Wv, WkvT, 4096, 1024, 1024, 4096);
  k_transpose_w<<<dim3(128, 128), 256, 0, stream>>>(Wo, WoT, 4096, 4096, 0, 4096);
  k_rope_tab<<<512, 256, 0, stream>>>(pos, tab);

  k_gemm_bt<u16><<<32 * 32, 256, 0, stream>>>(Xb, WqT, Qb, 4096, 4096, 4096);
  k_gemm_bt<u16><<<32 * 16, 256, 0, stream>>>(Xb, WkvT, KVb, 4096, 2048, 4096);

  k_rmsrope<<<(T_TOK * NHEADS) / 4, 256, 0, stream>>>(Qb, qw, tab, NHEADS, 4096);
  k_rmsrope<<<(T_TOK * NKV) / 4, 256, 0, stream>>>(KVb, kw, tab, NKV, 2048);

  k_transpose_v<<<dim3(16, 64, 4), 256, 0, stream>>>(KVb, Vt);

  k_attn<<<BATCH * NHEADS * (S_LEN / 128), 256, 0, stream>>>(Qb, KVb, Vt, Oact);

  k_gemm_bt<float><<<32 * 32, 256, 0, stream>>>(Oact, WoT, out, 4096, 4096, 4096);
}

// Round 4
// 699.866 us; speedup vs baseline: 2.1447x; 1.1463x over previous
//
#include <hip/hip_runtime.h>
#include <stdint.h>
#include <stddef.h>

#define S_LEN 2048
#define BATCH 2
#define NHEADS 32
#define NKV 8
#define HD 128
#define HIDDEN 4096
#define T_TOK (BATCH * S_LEN)

typedef unsigned short u16;
typedef __attribute__((ext_vector_type(4))) float f32x4;
typedef __attribute__((ext_vector_type(16))) float f32x16;
typedef __attribute__((ext_vector_type(8))) short s16x8;
typedef __attribute__((ext_vector_type(4))) unsigned short u16x4;
typedef __attribute__((ext_vector_type(4))) unsigned int u32x4;

__device__ __forceinline__ u16 f2bf(float f) {
  unsigned int u = __builtin_bit_cast(unsigned int, f);
  unsigned int r = (u + 0x7FFFu + ((u >> 16) & 1u)) >> 16;
  return (u16)r;
}
__device__ __forceinline__ float bf2f(u16 h) {
  return __builtin_bit_cast(float, ((unsigned int)h) << 16);
}

__device__ __forceinline__ void gload16(const void* g, void* l) {
  __builtin_amdgcn_global_load_lds((__attribute__((address_space(1))) void*)g,
                                   (__attribute__((address_space(3))) void*)l,
                                   16, 0, 0);
}

__device__ __forceinline__ unsigned cvtpk(float a, float b) {
  unsigned r;
  asm("v_cvt_pk_bf16_f32 %0, %1, %2" : "=v"(r) : "v"(a), "v"(b));
  return r;
}
__device__ __forceinline__ void lohi_dup(unsigned W, unsigned& lo, unsigned& hi) {
  unsigned a = W, b = W;
  asm volatile("v_permlane32_swap_b32 %0, %1" : "+v"(a), "+v"(b));
  lo = a; hi = b;
}

// ---------------- convert f32 -> bf16 (8 elems / thread) ----------------
__global__ __launch_bounds__(256) void k_convert(const float* __restrict__ in,
                                                 u16* __restrict__ out, int n8) {
  int i = blockIdx.x * 256 + threadIdx.x;
  if (i >= n8) return;
  float4 a = ((const float4*)in)[i * 2];
  float4 b = ((const float4*)in)[i * 2 + 1];
  u16x4 lo = {f2bf(a.x), f2bf(a.y), f2bf(a.z), f2bf(a.w)};
  u16x4 hi = {f2bf(b.x), f2bf(b.y), f2bf(b.z), f2bf(b.w)};
  ((u16x4*)out)[i * 2] = lo;
  ((u16x4*)out)[i * 2 + 1] = hi;
}

// ------------- transpose-convert W [K][N] f32 -> Wt [N][K] bf16 ----------
__global__ __launch_bounds__(256) void k_transpose_w(const float* __restrict__ W,
                                                     u16* __restrict__ Wt, int K,
                                                     int N, int outRowOff,
                                                     int outStride) {
  __shared__ float tl[32][33];
  int k0 = blockIdx.x * 32, n0 = blockIdx.y * 32;
  int t = threadIdx.x;
  int r = t >> 3, c4 = (t & 7) * 4;
  float4 v = *(const float4*)&W[(size_t)(k0 + r) * N + n0 + c4];
  tl[r][c4] = v.x; tl[r][c4 + 1] = v.y; tl[r][c4 + 2] = v.z; tl[r][c4 + 3] = v.w;
  __syncthreads();
  u16x4 o = {f2bf(tl[c4][r]), f2bf(tl[c4 + 1][r]), f2bf(tl[c4 + 2][r]),
             f2bf(tl[c4 + 3][r])};
  *(u16x4*)&Wt[(size_t)(outRowOff + n0 + r) * outStride + k0 + c4] = o;
}

// ---------------- RoPE cos/sin table: tab[s][0:64]=cos, [64:128]=sin -----
__global__ __launch_bounds__(256) void k_rope_tab(const int* __restrict__ pos,
                                                  float* __restrict__ tab) {
  int i = blockIdx.x * 256 + threadIdx.x;  // S*64
  int s = i >> 6, l = i & 63;
  float p = (float)pos[s];
  float ang = p * expf(-(float)l * 0.14391156516342163f);
  tab[s * 128 + l] = cosf(ang);
  tab[s * 128 + 64 + l] = sinf(ang);
}

// ===== 256x256xBK64 8-wave deep-pipelined GEMM: C = A[M][K] * Bt[N][K]^T =====
// T1 XCD swizzle, T2 LDS xor-swizzle, T3/T4 raw-barrier pipeline with counted
// drain (vmcnt only at tile boundary), T5 setprio around MFMA clusters.
// LDS: 128 KiB (A,B tiles double-buffered, [256 rows][64 k] bf16, 128B rows,
// read pos ^= row&7; staged via global_load_lds with inverse-swizzled source).
template <typename OutT>
__global__ __launch_bounds__(512, 2) void k_gemm256(const u16* __restrict__ A,
                                                    const u16* __restrict__ Bt,
                                                    OutT* __restrict__ C,
                                                    int M, int N, int K) {
  __shared__ u16 As[2][16384];
  __shared__ u16 Bs[2][16384];
  int nbn = N >> 8;
  int nwg = gridDim.x;
  int orig = blockIdx.x;
  int q8 = nwg >> 3, r8 = nwg & 7;
  int xcd = orig & 7, sub = orig >> 3;
  int wgid = (xcd < r8 ? xcd * (q8 + 1) : r8 * (q8 + 1) + (xcd - r8) * q8) + sub;
  int bm = wgid / nbn, bn = wgid % nbn;
  int tid = threadIdx.x, wid = tid >> 6, lane = tid & 63;
  int wm = wid >> 2, wn = wid & 3;
  int g = lane >> 4, c = lane & 15;
  int l3 = lane >> 3, l7 = lane & 7;
  int xpos = (l7 ^ l3) * 8;  // inverse-swizzled 16B position within 128B row

  f32x4 acc[8][4];
#pragma unroll
  for (int m = 0; m < 8; m++)
#pragma unroll
    for (int n = 0; n < 4; n++) acc[m][n] = (f32x4){0.f, 0.f, 0.f, 0.f};

  // staging source base: instr j covers rows wid*32 + j*8 .. +7
  const u16* aSrc = A + (size_t)(bm * 256 + wid * 32 + l3) * K + xpos;
  const u16* bSrc = Bt + (size_t)(bn * 256 + wid * 32 + l3) * K + xpos;

  // prologue: stage tile 0 into buf 0
#pragma unroll
  for (int j = 0; j < 4; j++) {
    gload16(aSrc + (size_t)(j * 8) * K, &As[0][(wid * 4 + j) * 512]);
    gload16(bSrc + (size_t)(j * 8) * K, &Bs[0][(wid * 4 + j) * 512]);
  }
  asm volatile("s_waitcnt vmcnt(0)" ::: "memory");
  __builtin_amdgcn_s_barrier();

  int nt = K >> 6;
  int swz = (c & 7);
  for (int t = 0; t < nt; t++) {
    int cur = t & 1;
    const u16* Ab = &As[cur][0];
    const u16* Bb = &Bs[cur][0];
    bool pre = (t + 1 < nt);
    size_t koff = (size_t)(t + 1) << 6;
#pragma unroll
    for (int p = 0; p < 4; p++) {
      const int mh = p & 1, ks = p >> 1;
      int sz = ((ks * 4 + g) ^ swz) * 8;
      s16x8 af[4], bf[4];
#pragma unroll
      for (int mi = 0; mi < 4; mi++)
        af[mi] = *(const s16x8*)&Ab[(wm * 128 + (mh * 4 + mi) * 16 + c) * 64 + sz];
#pragma unroll
      for (int n = 0; n < 4; n++)
        bf[n] = *(const s16x8*)&Bb[(wn * 64 + n * 16 + c) * 64 + sz];
      if (p < 2 && pre) {  // stage next tile (phases 0-1, 4 instrs each)
#pragma unroll
        for (int j2 = 0; j2 < 2; j2++) {
          int j = p * 2 + j2;
          gload16(aSrc + (size_t)(j * 8) * K + koff, &As[cur ^ 1][(wid * 4 + j) * 512]);
          gload16(bSrc + (size_t)(j * 8) * K + koff, &Bs[cur ^ 1][(wid * 4 + j) * 512]);
        }
      }
      __builtin_amdgcn_s_barrier();
      asm volatile("s_waitcnt lgkmcnt(0)" ::: "memory");
      __builtin_amdgcn_sched_barrier(0);
      __builtin_amdgcn_s_setprio(1);
#pragma unroll
      for (int mi = 0; mi < 4; mi++)
#pragma unroll
        for (int n = 0; n < 4; n++)
          acc[mh * 4 + mi][n] = __builtin_amdgcn_mfma_f32_16x16x32_bf16(
              af[mi], bf[n], acc[mh * 4 + mi][n], 0, 0, 0);
      __builtin_amdgcn_s_setprio(0);
      if (p == 3 && pre)  // boundary drain: next tile fully landed
        asm volatile("s_waitcnt vmcnt(0)" ::: "memory");
      __builtin_amdgcn_s_barrier();
    }
  }
  // epilogue
#pragma unroll
  for (int m = 0; m < 8; m++)
#pragma unroll
    for (int n = 0; n < 4; n++) {
      size_t row = (size_t)bm * 256 + wm * 128 + m * 16 + g * 4;
      size_t col = (size_t)bn * 256 + wn * 64 + n * 16 + c;
#pragma unroll
      for (int r = 0; r < 4; r++) {
        float v = acc[m][n][r];
        if constexpr (sizeof(OutT) == 2)
          C[(row + r) * N + col] = (OutT)f2bf(v);
        else
          C[(row + r) * N + col] = (OutT)v;
      }
    }
}

// ------------- fused per-head RMSNorm + RoPE (in-place, bf16) ------------
__global__ __launch_bounds__(256) void k_rmsrope(u16* __restrict__ QK,
                                                 const float* __restrict__ w,
                                                 const float* __restrict__ tab,
                                                 int H, int rowStride) {
  int row = blockIdx.x * 4 + (threadIdx.x >> 6);
  int lane = threadIdx.x & 63;
  int t = row / H, h = row - t * H;
  int s = t & (S_LEN - 1);
  u16* p = QK + (size_t)t * rowStride + h * HD;
  float x1 = bf2f(p[lane]), x2 = bf2f(p[lane + 64]);
  float ss = x1 * x1 + x2 * x2;
#pragma unroll
  for (int o = 32; o >= 1; o >>= 1) ss += __shfl_xor(ss, o);
  float inv = rsqrtf(ss * (1.0f / 128.0f) + 1e-6f);
  float y1 = x1 * inv * w[lane], y2 = x2 * inv * w[lane + 64];
  float cs = tab[s * 128 + lane], sn = tab[s * 128 + 64 + lane];
  p[lane] = f2bf(y1 * cs - y2 * sn);
  p[lane + 64] = f2bf(y2 * cs + y1 * sn);
}

// --------- transpose V: KV[t][1024 + kh*128 + d] -> Vt[bkh*128+d][s] -----
__global__ __launch_bounds__(256) void k_transpose_v(const u16* __restrict__ KV,
                                                     u16* __restrict__ Vt) {
  __shared__ u16 tl[32][40];
  int bkh = blockIdx.x;
  int s0 = blockIdx.y * 32, d0 = blockIdx.z * 32;
  int b = bkh >> 3, kh = bkh & 7;
  int t = threadIdx.x, r = t >> 3, c4 = (t & 7) * 4;
  const u16* src =
      KV + (size_t)(b * S_LEN + s0 + r) * 2048 + 1024 + kh * HD + d0 + c4;
  u16x4 v = *(const u16x4*)src;
  tl[r][c4] = v[0]; tl[r][c4 + 1] = v[1]; tl[r][c4 + 2] = v[2]; tl[r][c4 + 3] = v[3];
  __syncthreads();
  u16x4 o = {tl[c4][r], tl[c4 + 1][r], tl[c4 + 2][r], tl[c4 + 3][r]};
  *(u16x4*)&Vt[(size_t)(bkh * HD + d0 + r) * S_LEN + s0 + c4] = o;
}

// --------------------------- causal GQA attention ------------------------
__global__ __launch_bounds__(256) void k_attn(const u16* __restrict__ Q,
                                              const u16* __restrict__ KV,
                                              const u16* __restrict__ Vt,
                                              u16* __restrict__ Oact) {
  __shared__ u16 Ks[2][64 * 128];
  __shared__ u16 Vs[2][128 * 64];
  int bid = blockIdx.x;
  int qt = 15 - (bid >> 6);
  int bh = bid & 63;
  int h = bh & 31, b = bh >> 5;
  int kh = h >> 2;
  int w = threadIdx.x >> 6, lane = threadIdx.x & 63;
  int q31 = lane & 31, hh = lane >> 5;
  int qw0 = qt * 128 + w * 32;
  const float scale = 0.08838834764831845f;

  s16x8 qf[8];
  const u16* Qp = Q + (size_t)(b * S_LEN + qw0 + q31) * 4096 + h * HD + hh * 8;
#pragma unroll
  for (int dc = 0; dc < 8; dc++) {
    s16x8 raw = *(const s16x8*)(Qp + dc * 16);
#pragma unroll
    for (int e = 0; e < 8; e++)
      qf[dc][e] = (short)f2bf(bf2f((u16)raw[e]) * scale);
  }

  f32x16 o[4];
#pragma unroll
  for (int d = 0; d < 4; d++)
#pragma unroll
    for (int r = 0; r < 16; r++) o[d][r] = 0.f;
  float m = -3.0e38f, l = 0.f;

  const char* Kg = (const char*)(KV + (size_t)b * S_LEN * 2048 + kh * HD);
  const char* Vg = (const char*)(Vt + (size_t)(b * 8 + kh) * HD * S_LEN);

  int nch = 2 * qt + 2;

  {
    char* KsB = (char*)Ks[0];
    char* VsB = (char*)Vs[0];
#pragma unroll
    for (int j = 0; j < 4; j++) {
      int ins = w * 4 + j;
      int row = ins * 4 + (lane >> 4);
      int bc = ((lane & 15) * 16) ^ ((row & 7) << 4);
      gload16(Kg + (size_t)row * 4096 + bc, KsB + ins * 1024);
    }
#pragma unroll
    for (int j = 0; j < 4; j++) {
      int ins = w * 4 + j;
      int row = ins * 8 + (lane >> 3);
      int bc = ((lane & 7) * 16) ^ ((row & 7) << 4);
      gload16(Vg + (size_t)row * 4096 + bc, VsB + ins * 1024);
    }
  }

  int cur = 0;
  for (int ch = 0; ch < nch; ch++) {
    int kb = ch * 64;
    __syncthreads();
    if (ch + 1 < nch) {
      char* KsB = (char*)Ks[cur ^ 1];
      char* VsB = (char*)Vs[cur ^ 1];
      int kb2 = kb + 64;
#pragma unroll
      for (int j = 0; j < 4; j++) {
        int ins = w * 4 + j;
        int row = ins * 4 + (lane >> 4);
        int bc = ((lane & 15) * 16) ^ ((row & 7) << 4);
        gload16(Kg + (size_t)(kb2 + row) * 4096 + bc, KsB + ins * 1024);
      }
#pragma unroll
      for (int j = 0; j < 4; j++) {
        int ins = w * 4 + j;
        int row = ins * 8 + (lane >> 3);
        int bc = ((lane & 7) * 16) ^ ((row & 7) << 4);
        gload16(Vg + (size_t)row * 4096 + (size_t)kb2 * 2 + bc, VsB + ins * 1024);
      }
    }
    if (kb <= qw0 + 31) {
      char* KsB = (char*)Ks[cur];
      char* VsB = (char*)Vs[cur];
      f32x16 sA, sB;
#pragma unroll
      for (int r = 0; r < 16; r++) { sA[r] = 0.f; sB[r] = 0.f; }
      int sw = (q31 & 7) << 4;
      __builtin_amdgcn_s_setprio(1);
#pragma unroll
      for (int dc = 0; dc < 8; dc++) {
        s16x8 kfA = *(const s16x8*)(KsB + q31 * 256 + ((dc * 32 + hh * 16) ^ sw));
        s16x8 kfB = *(const s16x8*)(KsB + (32 + q31) * 256 + ((dc * 32 + hh * 16) ^ sw));
        sA = __builtin_amdgcn_mfma_f32_32x32x16_bf16(kfA, qf[dc], sA, 0, 0, 0);
        sB = __builtin_amdgcn_mfma_f32_32x32x16_bf16(kfB, qf[dc], sB, 0, 0, 0);
      }
      __builtin_amdgcn_s_setprio(0);
      if (kb + 63 > qw0) {
        int qa = qw0 + q31;
#pragma unroll
        for (int r = 0; r < 16; r++) {
          int krow = (r & 3) + 8 * (r >> 2) + 4 * hh;
          if (kb + krow > qa) sA[r] = -1e30f;
          if (kb + 32 + krow > qa) sB[r] = -1e30f;
        }
      }
      float mx = -3.0e38f;
#pragma unroll
      for (int r = 0; r < 16; r++) mx = fmaxf(mx, fmaxf(sA[r], sB[r]));
      mx = fmaxf(mx, __shfl_xor(mx, 32));
      if (!__all(mx - m <= 8.0f)) {
        float mnew = fmaxf(m, mx);
        float corr = __expf(m - mnew);
        l *= corr;
#pragma unroll
        for (int d = 0; d < 4; d++)
#pragma unroll
          for (int r = 0; r < 16; r++) o[d][r] *= corr;
        m = mnew;
      }
      float rs = 0.f;
#pragma unroll
      for (int r = 0; r < 16; r++) {
        sA[r] = __expf(sA[r] - m); rs += sA[r];
        sB[r] = __expf(sB[r] - m); rs += sB[r];
      }
      rs += __shfl_xor(rs, 32);
      l += rs;
#pragma unroll
      for (int st = 0; st < 2; st++) {
        unsigned Aw[8], Bw[8];
#pragma unroll
        for (int j = 0; j < 8; j++) {
          float p0 = st ? sB[2 * j] : sA[2 * j];
          float p1 = st ? sB[2 * j + 1] : sA[2 * j + 1];
          lohi_dup(cvtpk(p0, p1), Aw[j], Bw[j]);
        }
#pragma unroll
        for (int kc2 = 0; kc2 < 2; kc2++) {
          u32x4 wv;
          wv.x = hh ? Aw[kc2 * 4 + 2] : Aw[kc2 * 4 + 0];
          wv.y = hh ? Aw[kc2 * 4 + 3] : Aw[kc2 * 4 + 1];
          wv.z = hh ? Bw[kc2 * 4 + 2] : Bw[kc2 * 4 + 0];
          wv.w = hh ? Bw[kc2 * 4 + 3] : Bw[kc2 * 4 + 1];
          s16x8 pf = __builtin_bit_cast(s16x8, wv);
          int kc = st * 2 + kc2;
          __builtin_amdgcn_s_setprio(1);
#pragma unroll
          for (int d = 0; d < 4; d++) {
            int row = d * 32 + q31;
            int vsw = (row & 7) << 4;
            s16x8 vf = *(const s16x8*)(VsB + row * 128 + ((kc * 32 + hh * 16) ^ vsw));
            o[d] = __builtin_amdgcn_mfma_f32_32x32x16_bf16(vf, pf, o[d], 0, 0, 0);
          }
          __builtin_amdgcn_s_setprio(0);
        }
      }
    }
    cur ^= 1;
  }
  float linv = 1.0f / l;
  u16* Op = Oact + (size_t)(b * S_LEN + qw0 + q31) * 4096 + h * HD;
#pragma unroll
  for (int d = 0; d < 4; d++)
#pragma unroll
    for (int g4 = 0; g4 < 4; g4++) {
      int d0 = d * 32 + 8 * g4 + 4 * hh;
      u16x4 w4 = {f2bf(o[d][4 * g4 + 0] * linv), f2bf(o[d][4 * g4 + 1] * linv),
                  f2bf(o[d][4 * g4 + 2] * linv), f2bf(o[d][4 * g4 + 3] * linv)};
      *(u16x4*)(Op + d0) = w4;
    }
}

extern "C" void kernel_launch(void* const* d_in, const int* in_sizes, int n_in,
                              void* d_out, int out_size, void* d_ws,
                              size_t ws_size, hipStream_t stream) {
  (void)in_sizes; (void)n_in; (void)out_size; (void)ws_size;
  const float* X = (const float*)d_in[0];
  const int* pos = (const int*)d_in[1];
  const float* Wq = (const float*)d_in[2];
  const float* Wk = (const float*)d_in[3];
  const float* Wv = (const float*)d_in[4];
  const float* Wo = (const float*)d_in[5];
  const float* qw = (const float*)d_in[6];
  const float* kw = (const float*)d_in[7];
  float* out = (float*)d_out;
  char* ws = (char*)d_ws;

  const size_t MB = 1024ull * 1024ull;
  u16* Xb    = (u16*)(ws + 0 * MB);
  u16* WqT   = (u16*)(ws + 32 * MB);
  u16* WkvT  = (u16*)(ws + 64 * MB);
  u16* WoT   = (u16*)(ws + 80 * MB);
  u16* Qb    = (u16*)(ws + 112 * MB);
  u16* KVb   = (u16*)(ws + 144 * MB);
  u16* Vt    = (u16*)(ws + 160 * MB);
  u16* Oact  = (u16*)(ws + 168 * MB);
  float* tab = (float*)(ws + 200 * MB);

  k_convert<<<8192, 256, 0, stream>>>(X, Xb, (T_TOK * HIDDEN) / 8);
  k_transpose_w<<<dim3(128, 128), 256, 0, stream>>>(Wq, WqT, 4096, 4096, 0, 4096);
  k_transpose_w<<<dim3(128, 32), 256, 0, stream>>>(Wk, WkvT, 4096, 1024, 0, 4096);
  k_transpose_w<<<dim3(128, 32), 256, 0, stream>>>(Wv, WkvT, 4096, 1024, 1024, 4096);
  k_transpose_w<<<dim3(128, 128), 256, 0, stream>>>(Wo, WoT, 4096, 4096, 0, 4096);
  k_rope_tab<<<512, 256, 0, stream>>>(pos, tab);

  k_gemm256<u16><<<16 * 16, 512, 0, stream>>>(Xb, WqT, Qb, 4096, 4096, 4096);
  k_gemm256<u16><<<16 * 8, 512, 0, stream>>>(Xb, WkvT, KVb, 4096, 2048, 4096);

  k_rmsrope<<<(T_TOK * NHEADS) / 4, 256, 0, stream>>>(Qb, qw, tab, NHEADS, 4096);
  k_rmsrope<<<(T_TOK * NKV) / 4, 256, 0, stream>>>(KVb, kw, tab, NKV, 2048);

  k_transpose_v<<<dim3(16, 64, 4), 256, 0, stream>>>(KVb, Vt);

  k_attn<<<BATCH * NHEADS * (S_LEN / 128), 256, 0, stream>>>(Qb, KVb, Vt, Oact);

  k_gemm256<float><<<16 * 16, 512, 0, stream>>>(Oact, WoT, out, 4096, 4096, 4096);
}

// Round 5
// 653.239 us; speedup vs baseline: 2.2978x; 1.0714x over previous
//
#include <hip/hip_runtime.h>
#include <stdint.h>
#include <stddef.h>

#define S_LEN 2048
#define BATCH 2
#define NHEADS 32
#define NKV 8
#define HD 128
#define HIDDEN 4096
#define T_TOK (BATCH * S_LEN)

typedef unsigned short u16;
typedef __attribute__((ext_vector_type(4))) float f32x4;
typedef __attribute__((ext_vector_type(16))) float f32x16;
typedef __attribute__((ext_vector_type(8))) short s16x8;
typedef __attribute__((ext_vector_type(4))) unsigned short u16x4;
typedef __attribute__((ext_vector_type(4))) unsigned int u32x4;

__device__ __forceinline__ u16 f2bf(float f) {
  unsigned int u = __builtin_bit_cast(unsigned int, f);
  unsigned int r = (u + 0x7FFFu + ((u >> 16) & 1u)) >> 16;
  return (u16)r;
}
__device__ __forceinline__ float bf2f(u16 h) {
  return __builtin_bit_cast(float, ((unsigned int)h) << 16);
}

__device__ __forceinline__ void gload16(const void* g, void* l) {
  __builtin_amdgcn_global_load_lds((__attribute__((address_space(1))) void*)g,
                                   (__attribute__((address_space(3))) void*)l,
                                   16, 0, 0);
}

__device__ __forceinline__ unsigned cvtpk(float a, float b) {
  unsigned r;
  asm("v_cvt_pk_bf16_f32 %0, %1, %2" : "=v"(r) : "v"(a), "v"(b));
  return r;
}
__device__ __forceinline__ void lohi_dup(unsigned W, unsigned& lo, unsigned& hi) {
  unsigned a = W, b = W;
  asm volatile("v_permlane32_swap_b32 %0, %1" : "+v"(a), "+v"(b));
  lo = a; hi = b;
}

// ---------------- convert f32 -> bf16 (8 elems / thread) ----------------
__global__ __launch_bounds__(256) void k_convert(const float* __restrict__ in,
                                                 u16* __restrict__ out, int n8) {
  int i = blockIdx.x * 256 + threadIdx.x;
  if (i >= n8) return;
  float4 a = ((const float4*)in)[i * 2];
  float4 b = ((const float4*)in)[i * 2 + 1];
  u16x4 lo = {f2bf(a.x), f2bf(a.y), f2bf(a.z), f2bf(a.w)};
  u16x4 hi = {f2bf(b.x), f2bf(b.y), f2bf(b.z), f2bf(b.w)};
  ((u16x4*)out)[i * 2] = lo;
  ((u16x4*)out)[i * 2 + 1] = hi;
}

// ------------- transpose-convert W [K][N] f32 -> Wt [N][K] bf16 ----------
__global__ __launch_bounds__(256) void k_transpose_w(const float* __restrict__ W,
                                                     u16* __restrict__ Wt, int K,
                                                     int N, int outRowOff,
                                                     int outStride) {
  __shared__ float tl[32][33];
  int k0 = blockIdx.x * 32, n0 = blockIdx.y * 32;
  int t = threadIdx.x;
  int r = t >> 3, c4 = (t & 7) * 4;
  float4 v = *(const float4*)&W[(size_t)(k0 + r) * N + n0 + c4];
  tl[r][c4] = v.x; tl[r][c4 + 1] = v.y; tl[r][c4 + 2] = v.z; tl[r][c4 + 3] = v.w;
  __syncthreads();
  u16x4 o = {f2bf(tl[c4][r]), f2bf(tl[c4 + 1][r]), f2bf(tl[c4 + 2][r]),
             f2bf(tl[c4 + 3][r])};
  *(u16x4*)&Wt[(size_t)(outRowOff + n0 + r) * outStride + k0 + c4] = o;
}

// ---------------- RoPE cos/sin table: tab[s][0:64]=cos, [64:128]=sin -----
__global__ __launch_bounds__(256) void k_rope_tab(const int* __restrict__ pos,
                                                  float* __restrict__ tab) {
  int i = blockIdx.x * 256 + threadIdx.x;  // S*64
  int s = i >> 6, l = i & 63;
  float p = (float)pos[s];
  float ang = p * expf(-(float)l * 0.14391156516342163f);
  tab[s * 128 + l] = cosf(ang);
  tab[s * 128 + 64 + l] = sinf(ang);
}

// ===== 256x256xBK64 8-wave GEMM, staggered-operand pipeline (m201-style) ====
// T1 XCD swizzle, T2 xor-swizzled LDS, T3/T4 counted vmcnt(4) (never 0 in
// steady state), T5 setprio. 4 phases/K-tile: P1{rdA0+rdB0, stgA(t+1)h0},
// P2{rdB1, stgA(t+1)h1}, P3{rdA1, stgB(t+2)h0}, P4{stgB(t+2)h1, vmcnt(4)}.
// A(t+1)->buf^1 (A region dead since t-1.P3); B(t+2)->buf (B dead after P2).
template <typename OutT>
__global__ __launch_bounds__(512, 2) void k_gemm256(const u16* __restrict__ A,
                                                    const u16* __restrict__ Bt,
                                                    OutT* __restrict__ C,
                                                    int N, int K) {
  __shared__ u16 As[2][16384];   // [buf][256 rows][64 k], swizzled
  __shared__ u16 Bs[2][16384];
  int nbn = N >> 8;
  int nwg = gridDim.x;
  int orig = blockIdx.x;
  int q8 = nwg >> 3, r8 = nwg & 7;
  int xcd = orig & 7, sub = orig >> 3;
  int wgid = (xcd < r8 ? xcd * (q8 + 1) : r8 * (q8 + 1) + (xcd - r8) * q8) + sub;
  int bm = wgid / nbn, bn = wgid % nbn;
  int tid = threadIdx.x, wid = tid >> 6, lane = tid & 63;
  int wm = wid >> 2, wn = wid & 3;  // 2 (M) x 4 (N) waves; wave tile 128x64
  int g = lane >> 4, c = lane & 15;
  int l3 = lane >> 3, l7 = lane & 7;
  int swz = c & 7;
  int xunit = (l7 ^ l3) * 8;  // inverse-swizzled k-offset (elems) for staging

  f32x4 acc[8][4];
#pragma unroll
  for (int m = 0; m < 8; m++)
#pragma unroll
    for (int n = 0; n < 4; n++) acc[m][n] = (f32x4){0.f, 0.f, 0.f, 0.f};

  const u16* aBase = A + (size_t)(bm * 256 + wid * 16 + l3) * K + xunit;
  const u16* bBase = Bt + (size_t)(bn * 256 + wid * 16 + l3) * K + xunit;

  auto stgA = [&](int buf, int h, int j, size_t koff) {
    gload16(aBase + (size_t)(h * 128 + j * 8) * K + koff,
            &As[buf][(h * 128 + wid * 16 + j * 8) * 64]);
  };
  auto stgB = [&](int buf, int h, int j, size_t koff) {
    gload16(bBase + (size_t)(h * 128 + j * 8) * K + koff,
            &Bs[buf][(h * 128 + wid * 16 + j * 8) * 64]);
  };

  int nt = K >> 6;
  // prologue: A(0),B(0) -> buf0; B(1) -> buf1 (B(1) issued LAST for vmcnt(4))
#pragma unroll
  for (int j = 0; j < 2; j++) {
    stgA(0, 0, j, 0); stgA(0, 1, j, 0);
    stgB(0, 0, j, 0); stgB(0, 1, j, 0);
  }
#pragma unroll
  for (int j = 0; j < 2; j++) { stgB(1, 0, j, 64); stgB(1, 1, j, 64); }
  asm volatile("s_waitcnt vmcnt(4)" ::: "memory");
  __builtin_amdgcn_s_barrier();

  for (int t = 0; t < nt; t++) {
    int cb = t & 1;
    const u16* Ab = &As[cb][0];
    const u16* Bb = &Bs[cb][0];
    size_t k1 = (size_t)(t + 1) << 6;
    size_t k2 = (size_t)(t + 2) << 6;
    bool s1 = (t + 1 < nt), s2 = (t + 2 < nt);
    s16x8 af[8], bf0[4], bf1[4];

    // ---- P1: read A-mh0(8) + B-nh0(4); stage A(t+1) h0 ----
#pragma unroll
    for (int mi = 0; mi < 4; mi++)
#pragma unroll
      for (int ks = 0; ks < 2; ks++)
        af[mi * 2 + ks] = *(const s16x8*)&Ab[(wm * 128 + mi * 16 + c) * 64 +
                                             (((ks * 4 + g) ^ swz) * 8)];
#pragma unroll
    for (int nj = 0; nj < 2; nj++)
#pragma unroll
      for (int ks = 0; ks < 2; ks++)
        bf0[nj * 2 + ks] = *(const s16x8*)&Bb[(wn * 64 + nj * 16 + c) * 64 +
                                              (((ks * 4 + g) ^ swz) * 8)];
    if (s1) { stgA(cb ^ 1, 0, 0, k1); stgA(cb ^ 1, 0, 1, k1); }
    __builtin_amdgcn_s_barrier();
    asm volatile("s_waitcnt lgkmcnt(0)" ::: "memory");
    __builtin_amdgcn_sched_barrier(0);
    __builtin_amdgcn_s_setprio(1);
#pragma unroll
    for (int mi = 0; mi < 4; mi++)
#pragma unroll
      for (int nj = 0; nj < 2; nj++)
#pragma unroll
        for (int ks = 0; ks < 2; ks++)
          acc[mi][nj] = __builtin_amdgcn_mfma_f32_16x16x32_bf16(
              af[mi * 2 + ks], bf0[nj * 2 + ks], acc[mi][nj], 0, 0, 0);
    __builtin_amdgcn_s_setprio(0);
    __builtin_amdgcn_s_barrier();

    // ---- P2: read B-nh1(4); stage A(t+1) h1 ----
#pragma unroll
    for (int nj = 0; nj < 2; nj++)
#pragma unroll
      for (int ks = 0; ks < 2; ks++)
        bf1[nj * 2 + ks] = *(const s16x8*)&Bb[(wn * 64 + (2 + nj) * 16 + c) * 64 +
                                              (((ks * 4 + g) ^ swz) * 8)];
    if (s1) { stgA(cb ^ 1, 1, 0, k1); stgA(cb ^ 1, 1, 1, k1); }
    __builtin_amdgcn_s_barrier();
    asm volatile("s_waitcnt lgkmcnt(0)" ::: "memory");
    __builtin_amdgcn_sched_barrier(0);
    __builtin_amdgcn_s_setprio(1);
#pragma unroll
    for (int mi = 0; mi < 4; mi++)
#pragma unroll
      for (int nj = 0; nj < 2; nj++)
#pragma unroll
        for (int ks = 0; ks < 2; ks++)
          acc[mi][2 + nj] = __builtin_amdgcn_mfma_f32_16x16x32_bf16(
              af[mi * 2 + ks], bf1[nj * 2 + ks], acc[mi][2 + nj], 0, 0, 0);
    __builtin_amdgcn_s_setprio(0);
    __builtin_amdgcn_s_barrier();

    // ---- P3: read A-mh1(8); stage B(t+2) h0 ----
#pragma unroll
    for (int mi = 0; mi < 4; mi++)
#pragma unroll
      for (int ks = 0; ks < 2; ks++)
        af[mi * 2 + ks] = *(const s16x8*)&Ab[(wm * 128 + 64 + mi * 16 + c) * 64 +
                                             (((ks * 4 + g) ^ swz) * 8)];
    if (s2) { stgB(cb, 0, 0, k2); stgB(cb, 0, 1, k2); }
    __builtin_amdgcn_s_barrier();
    asm volatile("s_waitcnt lgkmcnt(0)" ::: "memory");
    __builtin_amdgcn_sched_barrier(0);
    __builtin_amdgcn_s_setprio(1);
#pragma unroll
    for (int mi = 0; mi < 4; mi++)
#pragma unroll
      for (int nj = 0; nj < 2; nj++)
#pragma unroll
        for (int ks = 0; ks < 2; ks++)
          acc[4 + mi][nj] = __builtin_amdgcn_mfma_f32_16x16x32_bf16(
              af[mi * 2 + ks], bf0[nj * 2 + ks], acc[4 + mi][nj], 0, 0, 0);
    __builtin_amdgcn_s_setprio(0);
    __builtin_amdgcn_s_barrier();

    // ---- P4: stage B(t+2) h1; MFMA mh1 x nh1; counted drain ----
    if (s2) { stgB(cb, 1, 0, k2); stgB(cb, 1, 1, k2); }
    __builtin_amdgcn_s_setprio(1);
#pragma unroll
    for (int mi = 0; mi < 4; mi++)
#pragma unroll
      for (int nj = 0; nj < 2; nj++)
#pragma unroll
        for (int ks = 0; ks < 2; ks++)
          acc[4 + mi][2 + nj] = __builtin_amdgcn_mfma_f32_16x16x32_bf16(
              af[mi * 2 + ks], bf1[nj * 2 + ks], acc[4 + mi][2 + nj], 0, 0, 0);
    __builtin_amdgcn_s_setprio(0);
    if (s2)
      asm volatile("s_waitcnt vmcnt(4)" ::: "memory");
    else if (s1)
      asm volatile("s_waitcnt vmcnt(0)" ::: "memory");
    __builtin_amdgcn_s_barrier();
  }

  // epilogue
#pragma unroll
  for (int m = 0; m < 8; m++)
#pragma unroll
    for (int n = 0; n < 4; n++) {
      size_t row = (size_t)bm * 256 + wm * 128 + m * 16 + g * 4;
      size_t col = (size_t)bn * 256 + wn * 64 + n * 16 + c;
#pragma unroll
      for (int r = 0; r < 4; r++) {
        float v = acc[m][n][r];
        if constexpr (sizeof(OutT) == 2)
          C[(row + r) * N + col] = (OutT)f2bf(v);
        else
          C[(row + r) * N + col] = (OutT)v;
      }
    }
}

// ------------- fused per-head RMSNorm + RoPE (in-place, bf16) ------------
__global__ __launch_bounds__(256) void k_rmsrope(u16* __restrict__ QK,
                                                 const float* __restrict__ w,
                                                 const float* __restrict__ tab,
                                                 int H, int rowStride) {
  int row = blockIdx.x * 4 + (threadIdx.x >> 6);
  int lane = threadIdx.x & 63;
  int t = row / H, h = row - t * H;
  int s = t & (S_LEN - 1);
  u16* p = QK + (size_t)t * rowStride + h * HD;
  float x1 = bf2f(p[lane]), x2 = bf2f(p[lane + 64]);
  float ss = x1 * x1 + x2 * x2;
#pragma unroll
  for (int o = 32; o >= 1; o >>= 1) ss += __shfl_xor(ss, o);
  float inv = rsqrtf(ss * (1.0f / 128.0f) + 1e-6f);
  float y1 = x1 * inv * w[lane], y2 = x2 * inv * w[lane + 64];
  float cs = tab[s * 128 + lane], sn = tab[s * 128 + 64 + lane];
  p[lane] = f2bf(y1 * cs - y2 * sn);
  p[lane + 64] = f2bf(y2 * cs + y1 * sn);
}

// --------- transpose V: KV[t][1024 + kh*128 + d] -> Vt[bkh*128+d][s] -----
__global__ __launch_bounds__(256) void k_transpose_v(const u16* __restrict__ KV,
                                                     u16* __restrict__ Vt) {
  __shared__ u16 tl[32][40];
  int bkh = blockIdx.x;
  int s0 = blockIdx.y * 32, d0 = blockIdx.z * 32;
  int b = bkh >> 3, kh = bkh & 7;
  int t = threadIdx.x, r = t >> 3, c4 = (t & 7) * 4;
  const u16* src =
      KV + (size_t)(b * S_LEN + s0 + r) * 2048 + 1024 + kh * HD + d0 + c4;
  u16x4 v = *(const u16x4*)src;
  tl[r][c4] = v[0]; tl[r][c4 + 1] = v[1]; tl[r][c4 + 2] = v[2]; tl[r][c4 + 3] = v[3];
  __syncthreads();
  u16x4 o = {tl[c4][r], tl[c4 + 1][r], tl[c4 + 2][r], tl[c4 + 3][r]};
  *(u16x4*)&Vt[(size_t)(bkh * HD + d0 + r) * S_LEN + s0 + c4] = o;
}

// --------------------------- causal GQA attention ------------------------
__global__ __launch_bounds__(256) void k_attn(const u16* __restrict__ Q,
                                              const u16* __restrict__ KV,
                                              const u16* __restrict__ Vt,
                                              u16* __restrict__ Oact) {
  __shared__ u16 Ks[2][64 * 128];
  __shared__ u16 Vs[2][128 * 64];
  int bid = blockIdx.x;
  int qt = 15 - (bid >> 6);
  int bh = bid & 63;
  int h = bh & 31, b = bh >> 5;
  int kh = h >> 2;
  int w = threadIdx.x >> 6, lane = threadIdx.x & 63;
  int q31 = lane & 31, hh = lane >> 5;
  int qw0 = qt * 128 + w * 32;
  const float scale = 0.08838834764831845f;

  s16x8 qf[8];
  const u16* Qp = Q + (size_t)(b * S_LEN + qw0 + q31) * 4096 + h * HD + hh * 8;
#pragma unroll
  for (int dc = 0; dc < 8; dc++) {
    s16x8 raw = *(const s16x8*)(Qp + dc * 16);
#pragma unroll
    for (int e = 0; e < 8; e++)
      qf[dc][e] = (short)f2bf(bf2f((u16)raw[e]) * scale);
  }

  f32x16 o[4];
#pragma unroll
  for (int d = 0; d < 4; d++)
#pragma unroll
    for (int r = 0; r < 16; r++) o[d][r] = 0.f;
  float m = -3.0e38f, l = 0.f;

  const char* Kg = (const char*)(KV + (size_t)b * S_LEN * 2048 + kh * HD);
  const char* Vg = (const char*)(Vt + (size_t)(b * 8 + kh) * HD * S_LEN);

  int nch = 2 * qt + 2;

  {
    char* KsB = (char*)Ks[0];
    char* VsB = (char*)Vs[0];
#pragma unroll
    for (int j = 0; j < 4; j++) {
      int ins = w * 4 + j;
      int row = ins * 4 + (lane >> 4);
      int bc = ((lane & 15) * 16) ^ ((row & 7) << 4);
      gload16(Kg + (size_t)row * 4096 + bc, KsB + ins * 1024);
    }
#pragma unroll
    for (int j = 0; j < 4; j++) {
      int ins = w * 4 + j;
      int row = ins * 8 + (lane >> 3);
      int bc = ((lane & 7) * 16) ^ ((row & 7) << 4);
      gload16(Vg + (size_t)row * 4096 + bc, VsB + ins * 1024);
    }
  }

  int cur = 0;
  for (int ch = 0; ch < nch; ch++) {
    int kb = ch * 64;
    __syncthreads();
    if (ch + 1 < nch) {
      char* KsB = (char*)Ks[cur ^ 1];
      char* VsB = (char*)Vs[cur ^ 1];
      int kb2 = kb + 64;
#pragma unroll
      for (int j = 0; j < 4; j++) {
        int ins = w * 4 + j;
        int row = ins * 4 + (lane >> 4);
        int bc = ((lane & 15) * 16) ^ ((row & 7) << 4);
        gload16(Kg + (size_t)(kb2 + row) * 4096 + bc, KsB + ins * 1024);
      }
#pragma unroll
      for (int j = 0; j < 4; j++) {
        int ins = w * 4 + j;
        int row = ins * 8 + (lane >> 3);
        int bc = ((lane & 7) * 16) ^ ((row & 7) << 4);
        gload16(Vg + (size_t)row * 4096 + (size_t)kb2 * 2 + bc, VsB + ins * 1024);
      }
    }
    if (kb <= qw0 + 31) {
      char* KsB = (char*)Ks[cur];
      char* VsB = (char*)Vs[cur];
      f32x16 sA, sB;
#pragma unroll
      for (int r = 0; r < 16; r++) { sA[r] = 0.f; sB[r] = 0.f; }
      int sw = (q31 & 7) << 4;
      __builtin_amdgcn_s_setprio(1);
#pragma unroll
      for (int dc = 0; dc < 8; dc++) {
        s16x8 kfA = *(const s16x8*)(KsB + q31 * 256 + ((dc * 32 + hh * 16) ^ sw));
        s16x8 kfB = *(const s16x8*)(KsB + (32 + q31) * 256 + ((dc * 32 + hh * 16) ^ sw));
        sA = __builtin_amdgcn_mfma_f32_32x32x16_bf16(kfA, qf[dc], sA, 0, 0, 0);
        sB = __builtin_amdgcn_mfma_f32_32x32x16_bf16(kfB, qf[dc], sB, 0, 0, 0);
      }
      __builtin_amdgcn_s_setprio(0);
      if (kb + 63 > qw0) {
        int qa = qw0 + q31;
#pragma unroll
        for (int r = 0; r < 16; r++) {
          int krow = (r & 3) + 8 * (r >> 2) + 4 * hh;
          if (kb + krow > qa) sA[r] = -1e30f;
          if (kb + 32 + krow > qa) sB[r] = -1e30f;
        }
      }
      float mx = -3.0e38f;
#pragma unroll
      for (int r = 0; r < 16; r++) mx = fmaxf(mx, fmaxf(sA[r], sB[r]));
      mx = fmaxf(mx, __shfl_xor(mx, 32));
      if (!__all(mx - m <= 8.0f)) {
        float mnew = fmaxf(m, mx);
        float corr = __expf(m - mnew);
        l *= corr;
#pragma unroll
        for (int d = 0; d < 4; d++)
#pragma unroll
          for (int r = 0; r < 16; r++) o[d][r] *= corr;
        m = mnew;
      }
      float rs = 0.f;
#pragma unroll
      for (int r = 0; r < 16; r++) {
        sA[r] = __expf(sA[r] - m); rs += sA[r];
        sB[r] = __expf(sB[r] - m); rs += sB[r];
      }
      rs += __shfl_xor(rs, 32);
      l += rs;
#pragma unroll
      for (int st = 0; st < 2; st++) {
        unsigned Aw[8], Bw[8];
#pragma unroll
        for (int j = 0; j < 8; j++) {
          float p0 = st ? sB[2 * j] : sA[2 * j];
          float p1 = st ? sB[2 * j + 1] : sA[2 * j + 1];
          lohi_dup(cvtpk(p0, p1), Aw[j], Bw[j]);
        }
#pragma unroll
        for (int kc2 = 0; kc2 < 2; kc2++) {
          u32x4 wv;
          wv.x = hh ? Aw[kc2 * 4 + 2] : Aw[kc2 * 4 + 0];
          wv.y = hh ? Aw[kc2 * 4 + 3] : Aw[kc2 * 4 + 1];
          wv.z = hh ? Bw[kc2 * 4 + 2] : Bw[kc2 * 4 + 0];
          wv.w = hh ? Bw[kc2 * 4 + 3] : Bw[kc2 * 4 + 1];
          s16x8 pf = __builtin_bit_cast(s16x8, wv);
          int kc = st * 2 + kc2;
          __builtin_amdgcn_s_setprio(1);
#pragma unroll
          for (int d = 0; d < 4; d++) {
            int row = d * 32 + q31;
            int vsw = (row & 7) << 4;
            s16x8 vf = *(const s16x8*)(VsB + row * 128 + ((kc * 32 + hh * 16) ^ vsw));
            o[d] = __builtin_amdgcn_mfma_f32_32x32x16_bf16(vf, pf, o[d], 0, 0, 0);
          }
          __builtin_amdgcn_s_setprio(0);
        }
      }
    }
    cur ^= 1;
  }
  float linv = 1.0f / l;
  u16* Op = Oact + (size_t)(b * S_LEN + qw0 + q31) * 4096 + h * HD;
#pragma unroll
  for (int d = 0; d < 4; d++)
#pragma unroll
    for (int g4 = 0; g4 < 4; g4++) {
      int d0 = d * 32 + 8 * g4 + 4 * hh;
      u16x4 w4 = {f2bf(o[d][4 * g4 + 0] * linv), f2bf(o[d][4 * g4 + 1] * linv),
                  f2bf(o[d][4 * g4 + 2] * linv), f2bf(o[d][4 * g4 + 3] * linv)};
      *(u16x4*)(Op + d0) = w4;
    }
}

extern "C" void kernel_launch(void* const* d_in, const int* in_sizes, int n_in,
                              void* d_out, int out_size, void* d_ws,
                              size_t ws_size, hipStream_t stream) {
  (void)in_sizes; (void)n_in; (void)out_size; (void)ws_size;
  const float* X = (const float*)d_in[0];
  const int* pos = (const int*)d_in[1];
  const float* Wq = (const float*)d_in[2];
  const float* Wk = (const float*)d_in[3];
  const float* Wv = (const float*)d_in[4];
  const float* Wo = (const float*)d_in[5];
  const float* qw = (const float*)d_in[6];
  const float* kw = (const float*)d_in[7];
  float* out = (float*)d_out;
  char* ws = (char*)d_ws;

  const size_t MB = 1024ull * 1024ull;
  u16* Xb    = (u16*)(ws + 0 * MB);
  u16* WqT   = (u16*)(ws + 32 * MB);
  u16* WkvT  = (u16*)(ws + 64 * MB);
  u16* WoT   = (u16*)(ws + 80 * MB);
  u16* Qb    = (u16*)(ws + 112 * MB);
  u16* KVb   = (u16*)(ws + 144 * MB);
  u16* Vt    = (u16*)(ws + 160 * MB);
  u16* Oact  = (u16*)(ws + 168 * MB);
  float* tab = (float*)(ws + 200 * MB);

  k_convert<<<8192, 256, 0, stream>>>(X, Xb, (T_TOK * HIDDEN) / 8);
  k_transpose_w<<<dim3(128, 128), 256, 0, stream>>>(Wq, WqT, 4096, 4096, 0, 4096);
  k_transpose_w<<<dim3(128, 32), 256, 0, stream>>>(Wk, WkvT, 4096, 1024, 0, 4096);
  k_transpose_w<<<dim3(128, 32), 256, 0, stream>>>(Wv, WkvT, 4096, 1024, 1024, 4096);
  k_transpose_w<<<dim3(128, 128), 256, 0, stream>>>(Wo, WoT, 4096, 4096, 0, 4096);
  k_rope_tab<<<512, 256, 0, stream>>>(pos, tab);

  k_gemm256<u16><<<16 * 16, 512, 0, stream>>>(Xb, WqT, Qb, 4096, 4096);
  k_gemm256<u16><<<16 * 8, 512, 0, stream>>>(Xb, WkvT, KVb, 2048, 4096);

  k_rmsrope<<<(T_TOK * NHEADS) / 4, 256, 0, stream>>>(Qb, qw, tab, NHEADS, 4096);
  k_rmsrope<<<(T_TOK * NKV) / 4, 256, 0, stream>>>(KVb, kw, tab, NKV, 2048);

  k_transpose_v<<<dim3(16, 64, 4), 256, 0, stream>>>(KVb, Vt);

  k_attn<<<BATCH * NHEADS * (S_LEN / 128), 256, 0, stream>>>(Qb, KVb, Vt, Oact);

  k_gemm256<float><<<16 * 16, 512, 0, stream>>>(Oact, WoT, out, 4096, 4096);
}

// Round 7
// 639.584 us; speedup vs baseline: 2.3468x; 1.0213x over previous
//
#include <hip/hip_runtime.h>
#include <stdint.h>
#include <stddef.h>

#define S_LEN 2048
#define BATCH 2
#define NHEADS 32
#define NKV 8
#define HD 128
#define HIDDEN 4096
#define T_TOK (BATCH * S_LEN)

typedef unsigned short u16;
typedef __attribute__((ext_vector_type(4))) float f32x4;
typedef __attribute__((ext_vector_type(16))) float f32x16;
typedef __attribute__((ext_vector_type(8))) short s16x8;
typedef __attribute__((ext_vector_type(4))) unsigned short u16x4;
typedef __attribute__((ext_vector_type(4))) unsigned int u32x4;

__device__ __forceinline__ u16 f2bf(float f) {
  unsigned int u = __builtin_bit_cast(unsigned int, f);
  unsigned int r = (u + 0x7FFFu + ((u >> 16) & 1u)) >> 16;
  return (u16)r;
}
__device__ __forceinline__ float bf2f(u16 h) {
  return __builtin_bit_cast(float, ((unsigned int)h) << 16);
}

__device__ __forceinline__ void gload16(const void* g, void* l) {
  __builtin_amdgcn_global_load_lds((__attribute__((address_space(1))) void*)g,
                                   (__attribute__((address_space(3))) void*)l,
                                   16, 0, 0);
}

__device__ __forceinline__ unsigned cvtpk(float a, float b) {
  unsigned r;
  asm("v_cvt_pk_bf16_f32 %0, %1, %2" : "=v"(r) : "v"(a), "v"(b));
  return r;
}
__device__ __forceinline__ void lohi_dup(unsigned W, unsigned& lo, unsigned& hi) {
  unsigned a = W, b = W;
  asm volatile("v_permlane32_swap_b32 %0, %1" : "+v"(a), "+v"(b));
  lo = a; hi = b;
}

// ---------------- convert f32 -> bf16 (8 elems / thread) ----------------
__global__ __launch_bounds__(256) void k_convert(const float* __restrict__ in,
                                                 u16* __restrict__ out, int n8) {
  int i = blockIdx.x * 256 + threadIdx.x;
  if (i >= n8) return;
  float4 a = ((const float4*)in)[i * 2];
  float4 b = ((const float4*)in)[i * 2 + 1];
  u16x4 lo = {f2bf(a.x), f2bf(a.y), f2bf(a.z), f2bf(a.w)};
  u16x4 hi = {f2bf(b.x), f2bf(b.y), f2bf(b.z), f2bf(b.w)};
  ((u16x4*)out)[i * 2] = lo;
  ((u16x4*)out)[i * 2 + 1] = hi;
}

// ------------- transpose-convert W [K][N] f32 -> Wt [N][K] bf16 ----------
__global__ __launch_bounds__(256) void k_transpose_w(const float* __restrict__ W,
                                                     u16* __restrict__ Wt, int K,
                                                     int N, int outRowOff,
                                                     int outStride) {
  __shared__ float tl[32][33];
  int k0 = blockIdx.x * 32, n0 = blockIdx.y * 32;
  int t = threadIdx.x;
  int r = t >> 3, c4 = (t & 7) * 4;
  float4 v = *(const float4*)&W[(size_t)(k0 + r) * N + n0 + c4];
  tl[r][c4] = v.x; tl[r][c4 + 1] = v.y; tl[r][c4 + 2] = v.z; tl[r][c4 + 3] = v.w;
  __syncthreads();
  u16x4 o = {f2bf(tl[c4][r]), f2bf(tl[c4 + 1][r]), f2bf(tl[c4 + 2][r]),
             f2bf(tl[c4 + 3][r])};
  *(u16x4*)&Wt[(size_t)(outRowOff + n0 + r) * outStride + k0 + c4] = o;
}

// ---------------- RoPE cos/sin table: tab[s][0:64]=cos, [64:128]=sin -----
__global__ __launch_bounds__(256) void k_rope_tab(const int* __restrict__ pos,
                                                  float* __restrict__ tab) {
  int i = blockIdx.x * 256 + threadIdx.x;  // S*64
  int s = i >> 6, l = i & 63;
  float p = (float)pos[s];
  float ang = p * expf(-(float)l * 0.14391156516342163f);
  tab[s * 128 + l] = cosf(ang);
  tab[s * 128 + 64 + l] = sinf(ang);
}

// ===== 256x256xBK64 8-wave GEMM, staggered-operand pipeline (R5-proven) =====
// T1 XCD swizzle, T2 xor-swizzled LDS, T4 counted vmcnt(4) (never 0 in
// steady state), T5 setprio. 4 phases/K-tile: P1{rdA0+rdB0, stgA(t+1)h0},
// P2{rdB1, stgA(t+1)h1}, P3{rdA1, stgB(t+2)h0}, P4{stgB(t+2)h1, vmcnt(4)}.
// A(t+1)->buf^1 (A region dead since t-1.P3); B(t+2)->buf (B dead after P2).
// NOTE: every staged region's last read completed >=1 memory-asm boundary
// before the staging issue point (hoist-safe) -- do NOT retarget staging at
// regions read in the immediately-preceding phase (R6 regression).
template <typename OutT>
__global__ __launch_bounds__(512, 2) void k_gemm256(const u16* __restrict__ A,
                                                    const u16* __restrict__ Bt,
                                                    OutT* __restrict__ C,
                                                    int N, int K) {
  __shared__ u16 As[2][16384];   // [buf][256 rows][64 k], swizzled
  __shared__ u16 Bs[2][16384];
  int nbn = N >> 8;
  int nwg = gridDim.x;
  int orig = blockIdx.x;
  int q8 = nwg >> 3, r8 = nwg & 7;
  int xcd = orig & 7, sub = orig >> 3;
  int wgid = (xcd < r8 ? xcd * (q8 + 1) : r8 * (q8 + 1) + (xcd - r8) * q8) + sub;
  int bm = wgid / nbn, bn = wgid % nbn;
  int tid = threadIdx.x, wid = tid >> 6, lane = tid & 63;
  int wm = wid >> 2, wn = wid & 3;  // 2 (M) x 4 (N) waves; wave tile 128x64
  int g = lane >> 4, c = lane & 15;
  int l3 = lane >> 3, l7 = lane & 7;
  int swz = c & 7;
  int xunit = (l7 ^ l3) * 8;  // inverse-swizzled k-offset (elems) for staging

  f32x4 acc[8][4];
#pragma unroll
  for (int m = 0; m < 8; m++)
#pragma unroll
    for (int n = 0; n < 4; n++) acc[m][n] = (f32x4){0.f, 0.f, 0.f, 0.f};

  const u16* aBase = A + (size_t)(bm * 256 + wid * 16 + l3) * K + xunit;
  const u16* bBase = Bt + (size_t)(bn * 256 + wid * 16 + l3) * K + xunit;

  auto stgA = [&](int buf, int h, int j, size_t koff) {
    gload16(aBase + (size_t)(h * 128 + j * 8) * K + koff,
            &As[buf][(h * 128 + wid * 16 + j * 8) * 64]);
  };
  auto stgB = [&](int buf, int h, int j, size_t koff) {
    gload16(bBase + (size_t)(h * 128 + j * 8) * K + koff,
            &Bs[buf][(h * 128 + wid * 16 + j * 8) * 64]);
  };

  int nt = K >> 6;
  // prologue: A(0),B(0) -> buf0; B(1) -> buf1 (B(1) issued LAST for vmcnt(4))
#pragma unroll
  for (int j = 0; j < 2; j++) {
    stgA(0, 0, j, 0); stgA(0, 1, j, 0);
    stgB(0, 0, j, 0); stgB(0, 1, j, 0);
  }
#pragma unroll
  for (int j = 0; j < 2; j++) { stgB(1, 0, j, 64); stgB(1, 1, j, 64); }
  asm volatile("s_waitcnt vmcnt(4)" ::: "memory");
  __builtin_amdgcn_s_barrier();

  for (int t = 0; t < nt; t++) {
    int cb = t & 1;
    const u16* Ab = &As[cb][0];
    const u16* Bb = &Bs[cb][0];
    size_t k1 = (size_t)(t + 1) << 6;
    size_t k2 = (size_t)(t + 2) << 6;
    bool s1 = (t + 1 < nt), s2 = (t + 2 < nt);
    s16x8 af[8], bf0[4], bf1[4];

    // ---- P1: read A-mh0(8) + B-nh0(4); stage A(t+1) h0 ----
#pragma unroll
    for (int mi = 0; mi < 4; mi++)
#pragma unroll
      for (int ks = 0; ks < 2; ks++)
        af[mi * 2 + ks] = *(const s16x8*)&Ab[(wm * 128 + mi * 16 + c) * 64 +
                                             (((ks * 4 + g) ^ swz) * 8)];
#pragma unroll
    for (int nj = 0; nj < 2; nj++)
#pragma unroll
      for (int ks = 0; ks < 2; ks++)
        bf0[nj * 2 + ks] = *(const s16x8*)&Bb[(wn * 64 + nj * 16 + c) * 64 +
                                              (((ks * 4 + g) ^ swz) * 8)];
    if (s1) { stgA(cb ^ 1, 0, 0, k1); stgA(cb ^ 1, 0, 1, k1); }
    __builtin_amdgcn_s_barrier();
    asm volatile("s_waitcnt lgkmcnt(0)" ::: "memory");
    __builtin_amdgcn_sched_barrier(0);
    __builtin_amdgcn_s_setprio(1);
#pragma unroll
    for (int mi = 0; mi < 4; mi++)
#pragma unroll
      for (int nj = 0; nj < 2; nj++)
#pragma unroll
        for (int ks = 0; ks < 2; ks++)
          acc[mi][nj] = __builtin_amdgcn_mfma_f32_16x16x32_bf16(
              af[mi * 2 + ks], bf0[nj * 2 + ks], acc[mi][nj], 0, 0, 0);
    __builtin_amdgcn_s_setprio(0);
    __builtin_amdgcn_s_barrier();

    // ---- P2: read B-nh1(4); stage A(t+1) h1 ----
#pragma unroll
    for (int nj = 0; nj < 2; nj++)
#pragma unroll
      for (int ks = 0; ks < 2; ks++)
        bf1[nj * 2 + ks] = *(const s16x8*)&Bb[(wn * 64 + (2 + nj) * 16 + c) * 64 +
                                              (((ks * 4 + g) ^ swz) * 8)];
    if (s1) { stgA(cb ^ 1, 1, 0, k1); stgA(cb ^ 1, 1, 1, k1); }
    __builtin_amdgcn_s_barrier();
    asm volatile("s_waitcnt lgkmcnt(0)" ::: "memory");
    __builtin_amdgcn_sched_barrier(0);
    __builtin_amdgcn_s_setprio(1);
#pragma unroll
    for (int mi = 0; mi < 4; mi++)
#pragma unroll
      for (int nj = 0; nj < 2; nj++)
#pragma unroll
        for (int ks = 0; ks < 2; ks++)
          acc[mi][2 + nj] = __builtin_amdgcn_mfma_f32_16x16x32_bf16(
              af[mi * 2 + ks], bf1[nj * 2 + ks], acc[mi][2 + nj], 0, 0, 0);
    __builtin_amdgcn_s_setprio(0);
    __builtin_amdgcn_s_barrier();

    // ---- P3: read A-mh1(8); stage B(t+2) h0 ----
#pragma unroll
    for (int mi = 0; mi < 4; mi++)
#pragma unroll
      for (int ks = 0; ks < 2; ks++)
        af[mi * 2 + ks] = *(const s16x8*)&Ab[(wm * 128 + 64 + mi * 16 + c) * 64 +
                                             (((ks * 4 + g) ^ swz) * 8)];
    if (s2) { stgB(cb, 0, 0, k2); stgB(cb, 0, 1, k2); }
    __builtin_amdgcn_s_barrier();
    asm volatile("s_waitcnt lgkmcnt(0)" ::: "memory");
    __builtin_amdgcn_sched_barrier(0);
    __builtin_amdgcn_s_setprio(1);
#pragma unroll
    for (int mi = 0; mi < 4; mi++)
#pragma unroll
      for (int nj = 0; nj < 2; nj++)
#pragma unroll
        for (int ks = 0; ks < 2; ks++)
          acc[4 + mi][nj] = __builtin_amdgcn_mfma_f32_16x16x32_bf16(
              af[mi * 2 + ks], bf0[nj * 2 + ks], acc[4 + mi][nj], 0, 0, 0);
    __builtin_amdgcn_s_setprio(0);
    __builtin_amdgcn_s_barrier();

    // ---- P4: stage B(t+2) h1; MFMA mh1 x nh1; counted drain ----
    if (s2) { stgB(cb, 1, 0, k2); stgB(cb, 1, 1, k2); }
    __builtin_amdgcn_s_setprio(1);
#pragma unroll
    for (int mi = 0; mi < 4; mi++)
#pragma unroll
      for (int nj = 0; nj < 2; nj++)
#pragma unroll
        for (int ks = 0; ks < 2; ks++)
          acc[4 + mi][2 + nj] = __builtin_amdgcn_mfma_f32_16x16x32_bf16(
              af[mi * 2 + ks], bf1[nj * 2 + ks], acc[4 + mi][2 + nj], 0, 0, 0);
    __builtin_amdgcn_s_setprio(0);
    if (s2)
      asm volatile("s_waitcnt vmcnt(4)" ::: "memory");
    else if (s1)
      asm volatile("s_waitcnt vmcnt(0)" ::: "memory");
    __builtin_amdgcn_s_barrier();
  }

  // epilogue
#pragma unroll
  for (int m = 0; m < 8; m++)
#pragma unroll
    for (int n = 0; n < 4; n++) {
      size_t row = (size_t)bm * 256 + wm * 128 + m * 16 + g * 4;
      size_t col = (size_t)bn * 256 + wn * 64 + n * 16 + c;
#pragma unroll
      for (int r = 0; r < 4; r++) {
        float v = acc[m][n][r];
        if constexpr (sizeof(OutT) == 2)
          C[(row + r) * N + col] = (OutT)f2bf(v);
        else
          C[(row + r) * N + col] = (OutT)v;
      }
    }
}

// ------------- fused per-head RMSNorm + RoPE (in-place, bf16) ------------
__global__ __launch_bounds__(256) void k_rmsrope(u16* __restrict__ QK,
                                                 const float* __restrict__ w,
                                                 const float* __restrict__ tab,
                                                 int H, int rowStride) {
  int row = blockIdx.x * 4 + (threadIdx.x >> 6);
  int lane = threadIdx.x & 63;
  int t = row / H, h = row - t * H;
  int s = t & (S_LEN - 1);
  u16* p = QK + (size_t)t * rowStride + h * HD;
  float x1 = bf2f(p[lane]), x2 = bf2f(p[lane + 64]);
  float ss = x1 * x1 + x2 * x2;
#pragma unroll
  for (int o = 32; o >= 1; o >>= 1) ss += __shfl_xor(ss, o);
  float inv = rsqrtf(ss * (1.0f / 128.0f) + 1e-6f);
  float y1 = x1 * inv * w[lane], y2 = x2 * inv * w[lane + 64];
  float cs = tab[s * 128 + lane], sn = tab[s * 128 + 64 + lane];
  p[lane] = f2bf(y1 * cs - y2 * sn);
  p[lane + 64] = f2bf(y2 * cs + y1 * sn);
}

// --------- transpose V: KV[t][1024 + kh*128 + d] -> Vt[bkh*128+d][s] -----
__global__ __launch_bounds__(256) void k_transpose_v(const u16* __restrict__ KV,
                                                     u16* __restrict__ Vt) {
  __shared__ u16 tl[32][40];
  int bkh = blockIdx.x;
  int s0 = blockIdx.y * 32, d0 = blockIdx.z * 32;
  int b = bkh >> 3, kh = bkh & 7;
  int t = threadIdx.x, r = t >> 3, c4 = (t & 7) * 4;
  const u16* src =
      KV + (size_t)(b * S_LEN + s0 + r) * 2048 + 1024 + kh * HD + d0 + c4;
  u16x4 v = *(const u16x4*)src;
  tl[r][c4] = v[0]; tl[r][c4 + 1] = v[1]; tl[r][c4 + 2] = v[2]; tl[r][c4 + 3] = v[3];
  __syncthreads();
  u16x4 o = {tl[c4][r], tl[c4 + 1][r], tl[c4 + 2][r], tl[c4 + 3][r]};
  *(u16x4*)&Vt[(size_t)(bkh * HD + d0 + r) * S_LEN + s0 + c4] = o;
}

// --------------------------- causal GQA attention ------------------------
// 512 blocks, XCD-grouped: xcd = bid&7 owns 2 (b,kh) groups (KV L2-resident);
// each block = one (b,h), processes q-tile PAIR {p, 15-p} sequentially ->
// uniform 34 chunks/block, zero tail. Softmax in log2 domain (scale folds
// log2e). 32x32x16 MFMA, swapped QK^T, T12 repack, T13 defer-max,
// double-buffered LDS with overlapped staging (R5-proven chunk loop).
__global__ __launch_bounds__(256) void k_attn(const u16* __restrict__ Q,
                                              const u16* __restrict__ KV,
                                              const u16* __restrict__ Vt,
                                              u16* __restrict__ Oact) {
  __shared__ u16 Ks[2][64 * 128];
  __shared__ u16 Vs[2][128 * 64];
  int bid = blockIdx.x;
  int xcd = bid & 7, slot = bid >> 3;
  int grp = xcd * 2 + (slot >> 5);  // 16 groups = b*8 + kh
  int b = grp >> 3, kh = grp & 7;
  int s32 = slot & 31;
  int pr = s32 >> 2;
  int h = kh * 4 + (s32 & 3);
  int w = threadIdx.x >> 6, lane = threadIdx.x & 63;
  int q31 = lane & 31, hh = lane >> 5;
  const float qscale = 0.12751740810f;  // 1/sqrt(128) * log2(e)

  const char* Kg = (const char*)(KV + (size_t)b * S_LEN * 2048 + kh * HD);
  const char* Vg = (const char*)(Vt + (size_t)(b * 8 + kh) * HD * S_LEN);

#pragma unroll 1
  for (int half = 0; half < 2; half++) {
    __syncthreads();  // half-boundary safety: all prior LDS reads retired
    int qt = half ? 15 - pr : pr;
    int qw0 = qt * 128 + w * 32;

    // Q fragments (B operand: q = lane&31, d = dc*16 + hh*8 + e)
    s16x8 qf[8];
    const u16* Qp = Q + (size_t)(b * S_LEN + qw0 + q31) * 4096 + h * HD + hh * 8;
#pragma unroll
    for (int dc = 0; dc < 8; dc++) {
      s16x8 raw = *(const s16x8*)(Qp + dc * 16);
#pragma unroll
      for (int e = 0; e < 8; e++)
        qf[dc][e] = (short)f2bf(bf2f((u16)raw[e]) * qscale);
    }

    f32x16 o[4];
#pragma unroll
    for (int d = 0; d < 4; d++)
#pragma unroll
      for (int r = 0; r < 16; r++) o[d][r] = 0.f;
    float m = -3.0e38f, l = 0.f;

    int nch = 2 * qt + 2;

    // prologue: stage chunk 0 into buffer 0
    {
      char* KsB = (char*)Ks[0];
      char* VsB = (char*)Vs[0];
#pragma unroll
      for (int j = 0; j < 4; j++) {
        int ins = w * 4 + j;
        int row = ins * 4 + (lane >> 4);
        int bc = ((lane & 15) * 16) ^ ((row & 7) << 4);
        gload16(Kg + (size_t)row * 4096 + bc, KsB + ins * 1024);
      }
#pragma unroll
      for (int j = 0; j < 4; j++) {
        int ins = w * 4 + j;
        int row = ins * 8 + (lane >> 3);
        int bc = ((lane & 7) * 16) ^ ((row & 7) << 4);
        gload16(Vg + (size_t)row * 4096 + bc, VsB + ins * 1024);
      }
    }

    int cur = 0;
    for (int ch = 0; ch < nch; ch++) {
      int kb = ch * 64;
      __syncthreads();  // drains vmcnt (buf[cur] staged) + prev reads done
      if (ch + 1 < nch) {  // stage next chunk into buf[cur^1], overlapped
        char* KsB = (char*)Ks[cur ^ 1];
        char* VsB = (char*)Vs[cur ^ 1];
        int kb2 = kb + 64;
#pragma unroll
        for (int j = 0; j < 4; j++) {
          int ins = w * 4 + j;
          int row = ins * 4 + (lane >> 4);
          int bc = ((lane & 15) * 16) ^ ((row & 7) << 4);
          gload16(Kg + (size_t)(kb2 + row) * 4096 + bc, KsB + ins * 1024);
        }
#pragma unroll
        for (int j = 0; j < 4; j++) {
          int ins = w * 4 + j;
          int row = ins * 8 + (lane >> 3);
          int bc = ((lane & 7) * 16) ^ ((row & 7) << 4);
          gload16(Vg + (size_t)row * 4096 + (size_t)kb2 * 2 + bc, VsB + ins * 1024);
        }
      }
      if (kb <= qw0 + 31) {
        char* KsB = (char*)Ks[cur];
        char* VsB = (char*)Vs[cur];
        f32x16 sA, sB;
#pragma unroll
        for (int r = 0; r < 16; r++) { sA[r] = 0.f; sB[r] = 0.f; }
        int sw = (q31 & 7) << 4;
        __builtin_amdgcn_s_setprio(1);
#pragma unroll
        for (int dc = 0; dc < 8; dc++) {
          s16x8 kfA = *(const s16x8*)(KsB + q31 * 256 + ((dc * 32 + hh * 16) ^ sw));
          s16x8 kfB = *(const s16x8*)(KsB + (32 + q31) * 256 + ((dc * 32 + hh * 16) ^ sw));
          sA = __builtin_amdgcn_mfma_f32_32x32x16_bf16(kfA, qf[dc], sA, 0, 0, 0);
          sB = __builtin_amdgcn_mfma_f32_32x32x16_bf16(kfB, qf[dc], sB, 0, 0, 0);
        }
        __builtin_amdgcn_s_setprio(0);
        if (kb + 63 > qw0) {
          int qa = qw0 + q31;
#pragma unroll
          for (int r = 0; r < 16; r++) {
            int krow = (r & 3) + 8 * (r >> 2) + 4 * hh;
            if (kb + krow > qa) sA[r] = -1e30f;
            if (kb + 32 + krow > qa) sB[r] = -1e30f;
          }
        }
        float mx = -3.0e38f;
#pragma unroll
        for (int r = 0; r < 16; r++) mx = fmaxf(mx, fmaxf(sA[r], sB[r]));
        mx = fmaxf(mx, __shfl_xor(mx, 32));
        if (!__all(mx - m <= 11.5f)) {  // defer-max (T13, log2 units ~ 8 nats)
          float mnew = fmaxf(m, mx);
          float corr = __builtin_amdgcn_exp2f(m - mnew);
          l *= corr;
#pragma unroll
          for (int d = 0; d < 4; d++)
#pragma unroll
            for (int r = 0; r < 16; r++) o[d][r] *= corr;
          m = mnew;
        }
        float rs = 0.f;
#pragma unroll
        for (int r = 0; r < 16; r++) {
          sA[r] = __builtin_amdgcn_exp2f(sA[r] - m); rs += sA[r];
          sB[r] = __builtin_amdgcn_exp2f(sB[r] - m); rs += sB[r];
        }
        rs += __shfl_xor(rs, 32);
        l += rs;
#pragma unroll
        for (int st = 0; st < 2; st++) {
          unsigned Aw[8], Bw[8];
#pragma unroll
          for (int j = 0; j < 8; j++) {
            float p0 = st ? sB[2 * j] : sA[2 * j];
            float p1 = st ? sB[2 * j + 1] : sA[2 * j + 1];
            lohi_dup(cvtpk(p0, p1), Aw[j], Bw[j]);
          }
#pragma unroll
          for (int kc2 = 0; kc2 < 2; kc2++) {
            u32x4 wv;
            wv.x = hh ? Aw[kc2 * 4 + 2] : Aw[kc2 * 4 + 0];
            wv.y = hh ? Aw[kc2 * 4 + 3] : Aw[kc2 * 4 + 1];
            wv.z = hh ? Bw[kc2 * 4 + 2] : Bw[kc2 * 4 + 0];
            wv.w = hh ? Bw[kc2 * 4 + 3] : Bw[kc2 * 4 + 1];
            s16x8 pf = __builtin_bit_cast(s16x8, wv);
            int kc = st * 2 + kc2;
            __builtin_amdgcn_s_setprio(1);
#pragma unroll
            for (int d = 0; d < 4; d++) {
              int row = d * 32 + q31;
              int vsw = (row & 7) << 4;
              s16x8 vf = *(const s16x8*)(VsB + row * 128 + ((kc * 32 + hh * 16) ^ vsw));
              o[d] = __builtin_amdgcn_mfma_f32_32x32x16_bf16(vf, pf, o[d], 0, 0, 0);
            }
            __builtin_amdgcn_s_setprio(0);
          }
        }
      }
      cur ^= 1;
    }
    // epilogue: O^T C-layout -> Oact[token][h*128+d]
    float linv = 1.0f / l;
    u16* Op = Oact + (size_t)(b * S_LEN + qw0 + q31) * 4096 + h * HD;
#pragma unroll
    for (int d = 0; d < 4; d++)
#pragma unroll
      for (int g4 = 0; g4 < 4; g4++) {
        int d0 = d * 32 + 8 * g4 + 4 * hh;
        u16x4 w4 = {f2bf(o[d][4 * g4 + 0] * linv), f2bf(o[d][4 * g4 + 1] * linv),
                    f2bf(o[d][4 * g4 + 2] * linv), f2bf(o[d][4 * g4 + 3] * linv)};
        *(u16x4*)(Op + d0) = w4;
      }
  }
}

extern "C" void kernel_launch(void* const* d_in, const int* in_sizes, int n_in,
                              void* d_out, int out_size, void* d_ws,
                              size_t ws_size, hipStream_t stream) {
  (void)in_sizes; (void)n_in; (void)out_size; (void)ws_size;
  const float* X = (const float*)d_in[0];
  const int* pos = (const int*)d_in[1];
  const float* Wq = (const float*)d_in[2];
  const float* Wk = (const float*)d_in[3];
  const float* Wv = (const float*)d_in[4];
  const float* Wo = (const float*)d_in[5];
  const float* qw = (const float*)d_in[6];
  const float* kw = (const float*)d_in[7];
  float* out = (float*)d_out;
  char* ws = (char*)d_ws;

  const size_t MB = 1024ull * 1024ull;
  u16* Xb    = (u16*)(ws + 0 * MB);
  u16* WqT   = (u16*)(ws + 32 * MB);
  u16* WkvT  = (u16*)(ws + 64 * MB);
  u16* WoT   = (u16*)(ws + 80 * MB);
  u16* Qb    = (u16*)(ws + 112 * MB);
  u16* KVb   = (u16*)(ws + 144 * MB);
  u16* Vt    = (u16*)(ws + 160 * MB);
  u16* Oact  = (u16*)(ws + 168 * MB);
  float* tab = (float*)(ws + 200 * MB);

  k_convert<<<8192, 256, 0, stream>>>(X, Xb, (T_TOK * HIDDEN) / 8);
  k_transpose_w<<<dim3(128, 128), 256, 0, stream>>>(Wq, WqT, 4096, 4096, 0, 4096);
  k_transpose_w<<<dim3(128, 32), 256, 0, stream>>>(Wk, WkvT, 4096, 1024, 0, 4096);
  k_transpose_w<<<dim3(128, 32), 256, 0, stream>>>(Wv, WkvT, 4096, 1024, 1024, 4096);
  k_transpose_w<<<dim3(128, 128), 256, 0, stream>>>(Wo, WoT, 4096, 4096, 0, 4096);
  k_rope_tab<<<512, 256, 0, stream>>>(pos, tab);

  k_gemm256<u16><<<16 * 16, 512, 0, stream>>>(Xb, WqT, Qb, 4096, 4096);
  k_gemm256<u16><<<16 * 8, 512, 0, stream>>>(Xb, WkvT, KVb, 2048, 4096);

  k_rmsrope<<<(T_TOK * NHEADS) / 4, 256, 0, stream>>>(Qb, qw, tab, NHEADS, 4096);
  k_rmsrope<<<(T_TOK * NKV) / 4, 256, 0, stream>>>(KVb, kw, tab, NKV, 2048);

  k_transpose_v<<<dim3(16, 64, 4), 256, 0, stream>>>(KVb, Vt);

  k_attn<<<512, 256, 0, stream>>>(Qb, KVb, Vt, Oact);

  k_gemm256<float><<<16 * 16, 512, 0, stream>>>(Oact, WoT, out, 4096, 4096);
}

// Round 11
// 636.089 us; speedup vs baseline: 2.3597x; 1.0055x over previous
//
#include <hip/hip_runtime.h>
#include <stdint.h>
#include <stddef.h>

#define S_LEN 2048
#define BATCH 2
#define NHEADS 32
#define NKV 8
#define HD 128
#define HIDDEN 4096
#define T_TOK (BATCH * S_LEN)
// fused QKV activation row: [0,4096)=Q heads, [4096,5120)=K, [5120,6144)=V
#define QKV_W 6144

typedef unsigned short u16;
typedef __attribute__((ext_vector_type(4))) float f32x4;
typedef __attribute__((ext_vector_type(16))) float f32x16;
typedef __attribute__((ext_vector_type(8))) short s16x8;
typedef __attribute__((ext_vector_type(4))) unsigned short u16x4;
typedef __attribute__((ext_vector_type(4))) unsigned int u32x4;

__device__ __forceinline__ u16 f2bf(float f) {
  unsigned int u = __builtin_bit_cast(unsigned int, f);
  unsigned int r = (u + 0x7FFFu + ((u >> 16) & 1u)) >> 16;
  return (u16)r;
}
__device__ __forceinline__ float bf2f(u16 h) {
  return __builtin_bit_cast(float, ((unsigned int)h) << 16);
}

__device__ __forceinline__ void gload16(const void* g, void* l) {
  __builtin_amdgcn_global_load_lds((__attribute__((address_space(1))) void*)g,
                                   (__attribute__((address_space(3))) void*)l,
                                   16, 0, 0);
}

__device__ __forceinline__ unsigned cvtpk(float a, float b) {
  unsigned r;
  asm("v_cvt_pk_bf16_f32 %0, %1, %2" : "=v"(r) : "v"(a), "v"(b));
  return r;
}
__device__ __forceinline__ void lohi_dup(unsigned W, unsigned& lo, unsigned& hi) {
  unsigned a = W, b = W;
  asm volatile("v_permlane32_swap_b32 %0, %1" : "+v"(a), "+v"(b));
  lo = a; hi = b;
}

// ---------------- convert f32 -> bf16 (8 elems / thread) ----------------
__global__ __launch_bounds__(256) void k_convert(const float* __restrict__ in,
                                                 u16* __restrict__ out, int n8) {
  int i = blockIdx.x * 256 + threadIdx.x;
  if (i >= n8) return;
  float4 a = ((const float4*)in)[i * 2];
  float4 b = ((const float4*)in)[i * 2 + 1];
  u16x4 lo = {f2bf(a.x), f2bf(a.y), f2bf(a.z), f2bf(a.w)};
  u16x4 hi = {f2bf(b.x), f2bf(b.y), f2bf(b.z), f2bf(b.w)};
  ((u16x4*)out)[i * 2] = lo;
  ((u16x4*)out)[i * 2 + 1] = hi;
}

// ------------- transpose-convert W [K][N] f32 -> Wt [N][K] bf16 ----------
__global__ __launch_bounds__(256) void k_transpose_w(const float* __restrict__ W,
                                                     u16* __restrict__ Wt, int K,
                                                     int N, int outRowOff,
                                                     int outStride) {
  __shared__ float tl[32][33];
  int k0 = blockIdx.x * 32, n0 = blockIdx.y * 32;
  int t = threadIdx.x;
  int r = t >> 3, c4 = (t & 7) * 4;
  float4 v = *(const float4*)&W[(size_t)(k0 + r) * N + n0 + c4];
  tl[r][c4] = v.x; tl[r][c4 + 1] = v.y; tl[r][c4 + 2] = v.z; tl[r][c4 + 3] = v.w;
  __syncthreads();
  u16x4 o = {f2bf(tl[c4][r]), f2bf(tl[c4 + 1][r]), f2bf(tl[c4 + 2][r]),
             f2bf(tl[c4 + 3][r])};
  *(u16x4*)&Wt[(size_t)(outRowOff + n0 + r) * outStride + k0 + c4] = o;
}

// ---------------- RoPE cos/sin table: tab[s][0:64]=cos, [64:128]=sin -----
__global__ __launch_bounds__(256) void k_rope_tab(const int* __restrict__ pos,
                                                  float* __restrict__ tab) {
  int i = blockIdx.x * 256 + threadIdx.x;  // S*64
  int s = i >> 6, l = i & 63;
  float p = (float)pos[s];
  float ang = p * expf(-(float)l * 0.14391156516342163f);
  tab[s * 128 + l] = cosf(ang);
  tab[s * 128 + 64 + l] = sinf(ang);
}

// ===== 256x256xBK64 8-wave GEMM, staggered-operand pipeline (R5-proven) =====
// T1 XCD swizzle, T2 xor-swizzled LDS, T4 counted vmcnt(4) (never 0 in
// steady state; safe: 68 VGPRs, no spill vmem perturbs the count), T5
// setprio. 4 phases/K-tile: P1{rdA0+rdB0, stgA(t+1)h0}, P2{rdB1,
// stgA(t+1)h1}, P3{rdA1, stgB(t+2)h0}, P4{stgB(t+2)h1, vmcnt(4)}.
// REGION-LIFETIME MAP (R6's bug, understood): A half h0 = rows 0-127 of
// As[cb] is read in BOTH P1 (wm0 rows 0-63) and P3 (wm0 rows 64-127) --
// A may therefore NEVER be staged into the consumed buffer mid-iteration;
// it goes to buf^1 only. B half h0 (rows 0-127 of Bs) is last read at P2
// (wn0/wn1 stripes), so staging it at P3 leaves one full barrier; B h1
// last read P2 as well -> P4 stage safe.
template <typename OutT>
__global__ __launch_bounds__(512, 2) void k_gemm256(const u16* __restrict__ A,
                                                    const u16* __restrict__ Bt,
                                                    OutT* __restrict__ C,
                                                    int N, int K) {
  __shared__ u16 As[2][16384];   // [buf][256 rows][64 k], swizzled
  __shared__ u16 Bs[2][16384];
  int nbn = N >> 8;
  int nwg = gridDim.x;
  int orig = blockIdx.x;
  int q8 = nwg >> 3, r8 = nwg & 7;
  int xcd = orig & 7, sub = orig >> 3;
  int wgid = (xcd < r8 ? xcd * (q8 + 1) : r8 * (q8 + 1) + (xcd - r8) * q8) + sub;
  int bm = wgid / nbn, bn = wgid % nbn;
  int tid = threadIdx.x, wid = tid >> 6, lane = tid & 63;
  int wm = wid >> 2, wn = wid & 3;  // 2 (M) x 4 (N) waves; wave tile 128x64
  int g = lane >> 4, c = lane & 15;
  int l3 = lane >> 3, l7 = lane & 7;
  int swz = c & 7;
  int xunit = (l7 ^ l3) * 8;  // inverse-swizzled k-offset (elems) for staging

  f32x4 acc[8][4];
#pragma unroll
  for (int m = 0; m < 8; m++)
#pragma unroll
    for (int n = 0; n < 4; n++) acc[m][n] = (f32x4){0.f, 0.f, 0.f, 0.f};

  const u16* aBase = A + (size_t)(bm * 256 + wid * 16 + l3) * K + xunit;
  const u16* bBase = Bt + (size_t)(bn * 256 + wid * 16 + l3) * K + xunit;

  auto stgA = [&](int buf, int h, int j, size_t koff) {
    gload16(aBase + (size_t)(h * 128 + j * 8) * K + koff,
            &As[buf][(h * 128 + wid * 16 + j * 8) * 64]);
  };
  auto stgB = [&](int buf, int h, int j, size_t koff) {
    gload16(bBase + (size_t)(h * 128 + j * 8) * K + koff,
            &Bs[buf][(h * 128 + wid * 16 + j * 8) * 64]);
  };

  int nt = K >> 6;
  // prologue: A(0),B(0) -> buf0; B(1) -> buf1 (B(1) issued LAST for vmcnt(4))
#pragma unroll
  for (int j = 0; j < 2; j++) {
    stgA(0, 0, j, 0); stgA(0, 1, j, 0);
    stgB(0, 0, j, 0); stgB(0, 1, j, 0);
  }
#pragma unroll
  for (int j = 0; j < 2; j++) { stgB(1, 0, j, 64); stgB(1, 1, j, 64); }
  asm volatile("s_waitcnt vmcnt(4)" ::: "memory");
  __builtin_amdgcn_s_barrier();

  for (int t = 0; t < nt; t++) {
    int cb = t & 1;
    const u16* Ab = &As[cb][0];
    const u16* Bb = &Bs[cb][0];
    size_t k1 = (size_t)(t + 1) << 6;
    size_t k2 = (size_t)(t + 2) << 6;
    bool s1 = (t + 1 < nt), s2 = (t + 2 < nt);
    s16x8 af[8], bf0[4], bf1[4];

    // ---- P1: read A-mh0(8) + B-nh0(4); stage A(t+1) h0 ----
#pragma unroll
    for (int mi = 0; mi < 4; mi++)
#pragma unroll
      for (int ks = 0; ks < 2; ks++)
        af[mi * 2 + ks] = *(const s16x8*)&Ab[(wm * 128 + mi * 16 + c) * 64 +
                                             (((ks * 4 + g) ^ swz) * 8)];
#pragma unroll
    for (int nj = 0; nj < 2; nj++)
#pragma unroll
      for (int ks = 0; ks < 2; ks++)
        bf0[nj * 2 + ks] = *(const s16x8*)&Bb[(wn * 64 + nj * 16 + c) * 64 +
                                              (((ks * 4 + g) ^ swz) * 8)];
    if (s1) { stgA(cb ^ 1, 0, 0, k1); stgA(cb ^ 1, 0, 1, k1); }
    __builtin_amdgcn_s_barrier();
    asm volatile("s_waitcnt lgkmcnt(0)" ::: "memory");
    __builtin_amdgcn_sched_barrier(0);
    __builtin_amdgcn_s_setprio(1);
#pragma unroll
    for (int mi = 0; mi < 4; mi++)
#pragma unroll
      for (int nj = 0; nj < 2; nj++)
#pragma unroll
        for (int ks = 0; ks < 2; ks++)
          acc[mi][nj] = __builtin_amdgcn_mfma_f32_16x16x32_bf16(
              af[mi * 2 + ks], bf0[nj * 2 + ks], acc[mi][nj], 0, 0, 0);
    __builtin_amdgcn_s_setprio(0);
    __builtin_amdgcn_s_barrier();

    // ---- P2: read B-nh1(4); stage A(t+1) h1 ----
#pragma unroll
    for (int nj = 0; nj < 2; nj++)
#pragma unroll
      for (int ks = 0; ks < 2; ks++)
        bf1[nj * 2 + ks] = *(const s16x8*)&Bb[(wn * 64 + (2 + nj) * 16 + c) * 64 +
                                              (((ks * 4 + g) ^ swz) * 8)];
    if (s1) { stgA(cb ^ 1, 1, 0, k1); stgA(cb ^ 1, 1, 1, k1); }
    __builtin_amdgcn_s_barrier();
    asm volatile("s_waitcnt lgkmcnt(0)" ::: "memory");
    __builtin_amdgcn_sched_barrier(0);
    __builtin_amdgcn_s_setprio(1);
#pragma unroll
    for (int mi = 0; mi < 4; mi++)
#pragma unroll
      for (int nj = 0; nj < 2; nj++)
#pragma unroll
        for (int ks = 0; ks < 2; ks++)
          acc[mi][2 + nj] = __builtin_amdgcn_mfma_f32_16x16x32_bf16(
              af[mi * 2 + ks], bf1[nj * 2 + ks], acc[mi][2 + nj], 0, 0, 0);
    __builtin_amdgcn_s_setprio(0);
    __builtin_amdgcn_s_barrier();

    // ---- P3: read A-mh1(8); stage B(t+2) h0 ----
#pragma unroll
    for (int mi = 0; mi < 4; mi++)
#pragma unroll
      for (int ks = 0; ks < 2; ks++)
        af[mi * 2 + ks] = *(const s16x8*)&Ab[(wm * 128 + 64 + mi * 16 + c) * 64 +
                                             (((ks * 4 + g) ^ swz) * 8)];
    if (s2) { stgB(cb, 0, 0, k2); stgB(cb, 0, 1, k2); }
    __builtin_amdgcn_s_barrier();
    asm volatile("s_waitcnt lgkmcnt(0)" ::: "memory");
    __builtin_amdgcn_sched_barrier(0);
    __builtin_amdgcn_s_setprio(1);
#pragma unroll
    for (int mi = 0; mi < 4; mi++)
#pragma unroll
      for (int nj = 0; nj < 2; nj++)
#pragma unroll
        for (int ks = 0; ks < 2; ks++)
          acc[4 + mi][nj] = __builtin_amdgcn_mfma_f32_16x16x32_bf16(
              af[mi * 2 + ks], bf0[nj * 2 + ks], acc[4 + mi][nj], 0, 0, 0);
    __builtin_amdgcn_s_setprio(0);
    __builtin_amdgcn_s_barrier();

    // ---- P4: stage B(t+2) h1; MFMA mh1 x nh1; counted drain ----
    if (s2) { stgB(cb, 1, 0, k2); stgB(cb, 1, 1, k2); }
    __builtin_amdgcn_s_setprio(1);
#pragma unroll
    for (int mi = 0; mi < 4; mi++)
#pragma unroll
      for (int nj = 0; nj < 2; nj++)
#pragma unroll
        for (int ks = 0; ks < 2; ks++)
          acc[4 + mi][2 + nj] = __builtin_amdgcn_mfma_f32_16x16x32_bf16(
              af[mi * 2 + ks], bf1[nj * 2 + ks], acc[4 + mi][2 + nj], 0, 0, 0);
    __builtin_amdgcn_s_setprio(0);
    if (s2)
      asm volatile("s_waitcnt vmcnt(4)" ::: "memory");
    else if (s1)
      asm volatile("s_waitcnt vmcnt(0)" ::: "memory");
    __builtin_amdgcn_s_barrier();
  }

  // epilogue
#pragma unroll
  for (int m = 0; m < 8; m++)
#pragma unroll
    for (int n = 0; n < 4; n++) {
      size_t row = (size_t)bm * 256 + wm * 128 + m * 16 + g * 4;
      size_t col = (size_t)bn * 256 + wn * 64 + n * 16 + c;
#pragma unroll
      for (int r = 0; r < 4; r++) {
        float v = acc[m][n][r];
        if constexpr (sizeof(OutT) == 2)
          C[(row + r) * N + col] = (OutT)f2bf(v);
        else
          C[(row + r) * N + col] = (OutT)v;
      }
    }
}

// ------------- fused per-head RMSNorm + RoPE (in-place, bf16) ------------
__global__ __launch_bounds__(256) void k_rmsrope(u16* __restrict__ QK,
                                                 const float* __restrict__ w,
                                                 const float* __restrict__ tab,
                                                 int H, int rowStride) {
  int row = blockIdx.x * 4 + (threadIdx.x >> 6);
  int lane = threadIdx.x & 63;
  int t = row / H, h = row - t * H;
  int s = t & (S_LEN - 1);
  u16* p = QK + (size_t)t * rowStride + h * HD;
  float x1 = bf2f(p[lane]), x2 = bf2f(p[lane + 64]);
  float ss = x1 * x1 + x2 * x2;
#pragma unroll
  for (int o = 32; o >= 1; o >>= 1) ss += __shfl_xor(ss, o);
  float inv = rsqrtf(ss * (1.0f / 128.0f) + 1e-6f);
  float y1 = x1 * inv * w[lane], y2 = x2 * inv * w[lane + 64];
  float cs = tab[s * 128 + lane], sn = tab[s * 128 + 64 + lane];
  p[lane] = f2bf(y1 * cs - y2 * sn);
  p[lane + 64] = f2bf(y2 * cs + y1 * sn);
}

// ---- transpose V: QKV[t][5120 + kh*128 + d] -> Vt[bkh*128+d][s] ----
__global__ __launch_bounds__(256) void k_transpose_v(const u16* __restrict__ QKV,
                                                     u16* __restrict__ Vt) {
  __shared__ u16 tl[32][40];
  int bkh = blockIdx.x;
  int s0 = blockIdx.y * 32, d0 = blockIdx.z * 32;
  int b = bkh >> 3, kh = bkh & 7;
  int t = threadIdx.x, r = t >> 3, c4 = (t & 7) * 4;
  const u16* src =
      QKV + (size_t)(b * S_LEN + s0 + r) * QKV_W + 5120 + kh * HD + d0 + c4;
  u16x4 v = *(const u16x4*)src;
  tl[r][c4] = v[0]; tl[r][c4 + 1] = v[1]; tl[r][c4 + 2] = v[2]; tl[r][c4 + 3] = v[3];
  __syncthreads();
  u16x4 o = {tl[c4][r], tl[c4 + 1][r], tl[c4 + 2][r], tl[c4 + 3][r]};
  *(u16x4*)&Vt[(size_t)(bkh * HD + d0 + r) * S_LEN + s0 + c4] = o;
}

// --------------------------- causal GQA attention ------------------------
// R7-PROVEN structure (do not touch sync): 512 blocks, XCD-grouped (xcd owns
// 2 (b,kh) groups -> KV L2-resident); each block = one (b,h) processing
// q-tile PAIR {p, 15-p} -> uniform 34 chunks. K,V both double-buffered in
// 64 KiB LDS; ONE __syncthreads per chunk (stages next chunk into buf^1).
// Log2-domain softmax, T12 repack, T13 defer-max, T5 setprio.
// Only change vs R7: Q/K read from fused QKV buffer (stride 6144, K at
// col 4096); V still from separate Vt.
__global__ __launch_bounds__(256) void k_attn(const u16* __restrict__ QKV,
                                              const u16* __restrict__ Vt,
                                              u16* __restrict__ Oact) {
  __shared__ u16 Ks[2][64 * 128];
  __shared__ u16 Vs[2][128 * 64];
  int bid = blockIdx.x;
  int xcd = bid & 7, slot = bid >> 3;
  int grp = xcd * 2 + (slot >> 5);  // 16 groups = b*8 + kh
  int b = grp >> 3, kh = grp & 7;
  int s32 = slot & 31;
  int pr = s32 >> 2;
  int h = kh * 4 + (s32 & 3);
  int w = threadIdx.x >> 6, lane = threadIdx.x & 63;
  int q31 = lane & 31, hh = lane >> 5;
  const float qscale = 0.12751740810f;  // 1/sqrt(128) * log2(e)

  const char* Kg = (const char*)(QKV + (size_t)b * S_LEN * QKV_W + 4096 + kh * HD);
  const char* Vg = (const char*)(Vt + (size_t)(b * 8 + kh) * HD * S_LEN);

#pragma unroll 1
  for (int half = 0; half < 2; half++) {
    __syncthreads();  // half-boundary safety: all prior LDS reads retired
    int qt = half ? 15 - pr : pr;
    int qw0 = qt * 128 + w * 32;

    // Q fragments (B operand: q = lane&31, d = dc*16 + hh*8 + e)
    s16x8 qf[8];
    const u16* Qp = QKV + (size_t)(b * S_LEN + qw0 + q31) * QKV_W + h * HD + hh * 8;
#pragma unroll
    for (int dc = 0; dc < 8; dc++) {
      s16x8 raw = *(const s16x8*)(Qp + dc * 16);
#pragma unroll
      for (int e = 0; e < 8; e++)
        qf[dc][e] = (short)f2bf(bf2f((u16)raw[e]) * qscale);
    }

    f32x16 o[4];
#pragma unroll
    for (int d = 0; d < 4; d++)
#pragma unroll
      for (int r = 0; r < 16; r++) o[d][r] = 0.f;
    float m = -3.0e38f, l = 0.f;

    int nch = 2 * qt + 2;

    // prologue: stage chunk 0 into buffer 0
    {
      char* KsB = (char*)Ks[0];
      char* VsB = (char*)Vs[0];
#pragma unroll
      for (int j = 0; j < 4; j++) {
        int ins = w * 4 + j;
        int row = ins * 4 + (lane >> 4);
        int bc = ((lane & 15) * 16) ^ ((row & 7) << 4);
        gload16(Kg + (size_t)row * 12288 + bc, KsB + ins * 1024);
      }
#pragma unroll
      for (int j = 0; j < 4; j++) {
        int ins = w * 4 + j;
        int row = ins * 8 + (lane >> 3);
        int bc = ((lane & 7) * 16) ^ ((row & 7) << 4);
        gload16(Vg + (size_t)row * 4096 + bc, VsB + ins * 1024);
      }
    }

    int cur = 0;
    for (int ch = 0; ch < nch; ch++) {
      int kb = ch * 64;
      __syncthreads();  // drains vmcnt (buf[cur] staged) + prev reads done
      if (ch + 1 < nch) {  // stage next chunk into buf[cur^1], overlapped
        char* KsB = (char*)Ks[cur ^ 1];
        char* VsB = (char*)Vs[cur ^ 1];
        int kb2 = kb + 64;
#pragma unroll
        for (int j = 0; j < 4; j++) {
          int ins = w * 4 + j;
          int row = ins * 4 + (lane >> 4);
          int bc = ((lane & 15) * 16) ^ ((row & 7) << 4);
          gload16(Kg + (size_t)(kb2 + row) * 12288 + bc, KsB + ins * 1024);
        }
#pragma unroll
        for (int j = 0; j < 4; j++) {
          int ins = w * 4 + j;
          int row = ins * 8 + (lane >> 3);
          int bc = ((lane & 7) * 16) ^ ((row & 7) << 4);
          gload16(Vg + (size_t)row * 4096 + (size_t)kb2 * 2 + bc, VsB + ins * 1024);
        }
      }
      if (kb <= qw0 + 31) {
        char* KsB = (char*)Ks[cur];
        char* VsB = (char*)Vs[cur];
        f32x16 sA, sB;
#pragma unroll
        for (int r = 0; r < 16; r++) { sA[r] = 0.f; sB[r] = 0.f; }
        int sw = (q31 & 7) << 4;
        __builtin_amdgcn_s_setprio(1);
#pragma unroll
        for (int dc = 0; dc < 8; dc++) {
          s16x8 kfA = *(const s16x8*)(KsB + q31 * 256 + ((dc * 32 + hh * 16) ^ sw));
          s16x8 kfB = *(const s16x8*)(KsB + (32 + q31) * 256 + ((dc * 32 + hh * 16) ^ sw));
          sA = __builtin_amdgcn_mfma_f32_32x32x16_bf16(kfA, qf[dc], sA, 0, 0, 0);
          sB = __builtin_amdgcn_mfma_f32_32x32x16_bf16(kfB, qf[dc], sB, 0, 0, 0);
        }
        __builtin_amdgcn_s_setprio(0);
        if (kb + 63 > qw0) {
          int qa = qw0 + q31;
#pragma unroll
          for (int r = 0; r < 16; r++) {
            int krow = (r & 3) + 8 * (r >> 2) + 4 * hh;
            if (kb + krow > qa) sA[r] = -1e30f;
            if (kb + 32 + krow > qa) sB[r] = -1e30f;
          }
        }
        float mx = -3.0e38f;
#pragma unroll
        for (int r = 0; r < 16; r++) mx = fmaxf(mx, fmaxf(sA[r], sB[r]));
        mx = fmaxf(mx, __shfl_xor(mx, 32));
        if (!__all(mx - m <= 11.5f)) {  // defer-max (T13, log2 units)
          float mnew = fmaxf(m, mx);
          float corr = __builtin_amdgcn_exp2f(m - mnew);
          l *= corr;
#pragma unroll
          for (int d = 0; d < 4; d++)
#pragma unroll
            for (int r = 0; r < 16; r++) o[d][r] *= corr;
          m = mnew;
        }
        float rs = 0.f;
#pragma unroll
        for (int r = 0; r < 16; r++) {
          sA[r] = __builtin_amdgcn_exp2f(sA[r] - m); rs += sA[r];
          sB[r] = __builtin_amdgcn_exp2f(sB[r] - m); rs += sB[r];
        }
        rs += __shfl_xor(rs, 32);
        l += rs;
#pragma unroll
        for (int st = 0; st < 2; st++) {
          unsigned Aw[8], Bw[8];
#pragma unroll
          for (int j = 0; j < 8; j++) {
            float p0 = st ? sB[2 * j] : sA[2 * j];
            float p1 = st ? sB[2 * j + 1] : sA[2 * j + 1];
            lohi_dup(cvtpk(p0, p1), Aw[j], Bw[j]);
          }
#pragma unroll
          for (int kc2 = 0; kc2 < 2; kc2++) {
            u32x4 wv;
            wv.x = hh ? Aw[kc2 * 4 + 2] : Aw[kc2 * 4 + 0];
            wv.y = hh ? Aw[kc2 * 4 + 3] : Aw[kc2 * 4 + 1];
            wv.z = hh ? Bw[kc2 * 4 + 2] : Bw[kc2 * 4 + 0];
            wv.w = hh ? Bw[kc2 * 4 + 3] : Bw[kc2 * 4 + 1];
            s16x8 pf = __builtin_bit_cast(s16x8, wv);
            int kc = st * 2 + kc2;
            __builtin_amdgcn_s_setprio(1);
#pragma unroll
            for (int d = 0; d < 4; d++) {
              int row = d * 32 + q31;
              int vsw = (row & 7) << 4;
              s16x8 vf = *(const s16x8*)(VsB + row * 128 + ((kc * 32 + hh * 16) ^ vsw));
              o[d] = __builtin_amdgcn_mfma_f32_32x32x16_bf16(vf, pf, o[d], 0, 0, 0);
            }
            __builtin_amdgcn_s_setprio(0);
          }
        }
      }
      cur ^= 1;
    }
    // epilogue: O^T C-layout -> Oact[token][h*128+d]
    float linv = 1.0f / l;
    u16* Op = Oact + (size_t)(b * S_LEN + qw0 + q31) * 4096 + h * HD;
#pragma unroll
    for (int d = 0; d < 4; d++)
#pragma unroll
      for (int g4 = 0; g4 < 4; g4++) {
        int d0 = d * 32 + 8 * g4 + 4 * hh;
        u16x4 w4 = {f2bf(o[d][4 * g4 + 0] * linv), f2bf(o[d][4 * g4 + 1] * linv),
                    f2bf(o[d][4 * g4 + 2] * linv), f2bf(o[d][4 * g4 + 3] * linv)};
        *(u16x4*)(Op + d0) = w4;
      }
  }
}

extern "C" void kernel_launch(void* const* d_in, const int* in_sizes, int n_in,
                              void* d_out, int out_size, void* d_ws,
                              size_t ws_size, hipStream_t stream) {
  (void)in_sizes; (void)n_in; (void)out_size; (void)ws_size;
  const float* X = (const float*)d_in[0];
  const int* pos = (const int*)d_in[1];
  const float* Wq = (const float*)d_in[2];
  const float* Wk = (const float*)d_in[3];
  const float* Wv = (const float*)d_in[4];
  const float* Wo = (const float*)d_in[5];
  const float* qw = (const float*)d_in[6];
  const float* kw = (const float*)d_in[7];
  float* out = (float*)d_out;
  char* ws = (char*)d_ws;

  const size_t MB = 1024ull * 1024ull;
  u16* Xb    = (u16*)(ws + 0 * MB);     // [4096][4096] bf16     32 MiB
  u16* WqkvT = (u16*)(ws + 32 * MB);    // [6144][4096] fused    48 MiB
  u16* WkvT  = (u16*)(ws + 64 * MB);    //   (rows 4096..6143 of WqkvT)
  u16* WoT   = (u16*)(ws + 80 * MB);    // [4096][4096]          32 MiB
  u16* QKV   = (u16*)(ws + 112 * MB);   // [4096][6144]          48 MiB
  u16* Vt    = (u16*)(ws + 160 * MB);   // [16*128][2048]         8 MiB
  u16* Oact  = (u16*)(ws + 168 * MB);   // [4096][4096]          32 MiB
  float* tab = (float*)(ws + 200 * MB); // [2048][128]            1 MiB

  k_convert<<<8192, 256, 0, stream>>>(X, Xb, (T_TOK * HIDDEN) / 8);
  k_transpose_w<<<dim3(128, 128), 256, 0, stream>>>(Wq, WqkvT, 4096, 4096, 0, 4096);
  k_transpose_w<<<dim3(128, 32), 256, 0, stream>>>(Wk, WkvT, 4096, 1024, 0, 4096);
  k_transpose_w<<<dim3(128, 32), 256, 0, stream>>>(Wv, WkvT, 4096, 1024, 1024, 4096);
  k_transpose_w<<<dim3(128, 128), 256, 0, stream>>>(Wo, WoT, 4096, 4096, 0, 4096);
  k_rope_tab<<<512, 256, 0, stream>>>(pos, tab);

  // fused QKV projection: [4096][4096] x [6144][4096]^T -> [4096][6144]
  k_gemm256<u16><<<16 * 24, 512, 0, stream>>>(Xb, WqkvT, QKV, QKV_W, 4096);

  k_rmsrope<<<(T_TOK * NHEADS) / 4, 256, 0, stream>>>(QKV, qw, tab, NHEADS, QKV_W);
  k_rmsrope<<<(T_TOK * NKV) / 4, 256, 0, stream>>>(QKV + 4096, kw, tab, NKV, QKV_W);

  k_transpose_v<<<dim3(16, 64, 4), 256, 0, stream>>>(QKV, Vt);

  k_attn<<<512, 256, 0, stream>>>(QKV, Vt, Oact);

  k_gemm256<float><<<16 * 16, 512, 0, stream>>>(Oact, WoT, out, 4096, 4096);
}